// Round 1
// baseline (1654.685 us; speedup 1.0000x reference)
//
#include <hip/hip_runtime.h>

typedef unsigned short U16;
typedef __attribute__((ext_vector_type(4))) float f32x4;
typedef __attribute__((ext_vector_type(8))) short short8;
typedef __attribute__((ext_vector_type(8))) __bf16 bf16x8;

#define Bsz 8
#define Lsz 4096
#define HID 1024
#define DIMV 512
#define D_INNER 1024
#define NHEADS 32
#define HEADDIM 32
#define D_STATE 64
#define CONV_DIM 1152
#define D_PROJ 2208
#define D_PROJ_PAD 2304
#define MROWS 32768

__device__ __forceinline__ float bf2f(U16 u) {
  return __builtin_bit_cast(float, (unsigned)(((unsigned)u) << 16));
}
__device__ __forceinline__ U16 f2bf(float f) {
  unsigned u = __builtin_bit_cast(unsigned, f);
  return (U16)((u + 0x7FFFu + ((u >> 16) & 1u)) >> 16);
}
__device__ __forceinline__ void gload_lds16(const void* g, void* l) {
  __builtin_amdgcn_global_load_lds((const __attribute__((address_space(1))) unsigned int*)g,
                                   (__attribute__((address_space(3))) unsigned int*)l, 16, 0, 0);
}

// ---------- tiny txt GEMM: txt[b][j] = text[b,0,:] @ W_txt + b_txt ----------
__global__ __launch_bounds__(512) void txt_kernel(const float* __restrict__ text,
                                                  const float* __restrict__ Wt,
                                                  const float* __restrict__ bt,
                                                  float* __restrict__ txt) {
  int b = blockIdx.x, j = threadIdx.x;
  float s = bt[j];
  const float* tp = text + (size_t)b * 77 * 768;
  for (int k = 0; k < 768; ++k) s += tp[k] * Wt[(size_t)k * 512 + j];
  txt[b * 512 + j] = s;
}

// ---------- f32 -> bf16 bulk convert (float4/ushort4) ----------
__global__ __launch_bounds__(256) void cvt_f2b_kernel(const float* __restrict__ in,
                                                      U16* __restrict__ out, int n4) {
  int i = blockIdx.x * 256 + threadIdx.x;
  if (i < n4) {
    float4 v = reinterpret_cast<const float4*>(in)[i];
    ushort4 o;
    o.x = f2bf(v.x); o.y = f2bf(v.y); o.z = f2bf(v.z); o.w = f2bf(v.w);
    reinterpret_cast<ushort4*>(out)[i] = o;
  }
}

// ---------- transpose + convert weights: in[K][N] f32 -> out[Npad][K] bf16 (zero pad) ----------
__global__ __launch_bounds__(256) void transpose_cvt_kernel(const float* __restrict__ in,
                                                            U16* __restrict__ out,
                                                            int K, int N, int Npad) {
  __shared__ U16 tile[32][33];
  int n0 = blockIdx.x * 32, k0 = blockIdx.y * 32;
  int tx = threadIdx.x, ty = threadIdx.y;
  #pragma unroll
  for (int i = 0; i < 4; ++i) {
    int k = k0 + ty + i * 8, n = n0 + tx;
    float v = (n < N) ? in[(size_t)k * N + n] : 0.f;
    tile[ty + i * 8][tx] = f2bf(v);
  }
  __syncthreads();
  #pragma unroll
  for (int i = 0; i < 4; ++i) {
    int n = n0 + ty + i * 8;
    out[(size_t)n * K + k0 + tx] = tile[tx][ty + i * 8];
  }
}

// ---------- bf16 MFMA GEMM: C[M][Nreal] = A[M][K] * Bt[n][k]^T (+bias, +txt per b) ----------
// 128x128 tile, BK=64, 4 waves, global_load_lds w/ XOR chunk swizzle (both sides).
template <int EPI>
__global__ __launch_bounds__(256) void gemm_kernel(const U16* __restrict__ A,
                                                   const U16* __restrict__ Bt,
                                                   U16* __restrict__ C,
                                                   const float* __restrict__ bias,
                                                   const float* __restrict__ txtv,
                                                   int M, int K, int Nreal) {
  __shared__ alignas(16) U16 As[128 * 64];
  __shared__ alignas(16) U16 Bs[128 * 64];
  const int tid = threadIdx.x;
  const int wid = tid >> 6, lane = tid & 63;
  const int lhi = lane >> 4, llo = lane & 15;
  const int m0 = blockIdx.x * 128;
  const int n0 = blockIdx.y * 128;
  const int wr = wid >> 1, wc = wid & 1;
  f32x4 acc[4][4] = {};

  for (int k0 = 0; k0 < K; k0 += 64) {
    __syncthreads();
    #pragma unroll
    for (int is = 0; is < 4; ++is) {
      int qbase = is * 256 + wid * 64;
      int q = qbase + lane;
      int r = q >> 3;
      int cc = (q & 7) ^ (r & 7);   // pre-swizzled global source chunk
      gload_lds16(A + (size_t)(m0 + r) * K + k0 + cc * 8, &As[qbase * 8]);
    }
    #pragma unroll
    for (int is = 0; is < 4; ++is) {
      int qbase = is * 256 + wid * 64;
      int q = qbase + lane;
      int r = q >> 3;
      int cc = (q & 7) ^ (r & 7);
      gload_lds16(Bt + (size_t)(n0 + r) * K + k0 + cc * 8, &Bs[qbase * 8]);
    }
    __syncthreads();
    #pragma unroll
    for (int kk = 0; kk < 64; kk += 32) {
      bf16x8 av[4], bv[4];
      #pragma unroll
      for (int i = 0; i < 4; ++i) {
        int ra = wr * 64 + i * 16 + llo;
        short8 a = *reinterpret_cast<const short8*>(
            &As[ra * 64 + ((((kk >> 3) + lhi) ^ (ra & 7)) << 3)]);
        av[i] = __builtin_bit_cast(bf16x8, a);
        int rb = wc * 64 + i * 16 + llo;
        short8 b = *reinterpret_cast<const short8*>(
            &Bs[rb * 64 + ((((kk >> 3) + lhi) ^ (rb & 7)) << 3)]);
        bv[i] = __builtin_bit_cast(bf16x8, b);
      }
      #pragma unroll
      for (int i = 0; i < 4; ++i)
        #pragma unroll
        for (int j = 0; j < 4; ++j)
          acc[i][j] = __builtin_amdgcn_mfma_f32_16x16x32_bf16(av[i], bv[j], acc[i][j], 0, 0, 0);
    }
  }
  const int b = m0 >> 12;  // 4096 rows per batch
  #pragma unroll
  for (int i = 0; i < 4; ++i) {
    int rbase = m0 + wr * 64 + i * 16 + lhi * 4;
    #pragma unroll
    for (int j = 0; j < 4; ++j) {
      int cg = n0 + wc * 64 + j * 16 + llo;
      if (cg < Nreal) {
        float badd = bias[cg] + (EPI ? txtv[b * 512 + cg] : 0.f);
        #pragma unroll
        for (int r = 0; r < 4; ++r)
          C[(size_t)(rbase + r) * Nreal + cg] = f2bf(acc[i][j][r] + badd);
      }
    }
  }
}

// ---------- LayerNorm rows of 512 (bf16 in/out) ----------
__global__ __launch_bounds__(128) void ln_kernel(const U16* __restrict__ tok,
                                                 U16* __restrict__ xo,
                                                 const float* __restrict__ w,
                                                 const float* __restrict__ bb) {
  int row = blockIdx.x, tid = threadIdx.x;
  const U16* rp = tok + (size_t)row * 512 + tid * 4;
  uint2 raw = *reinterpret_cast<const uint2*>(rp);
  float f0 = bf2f((U16)(raw.x & 0xffff)), f1 = bf2f((U16)(raw.x >> 16));
  float f2 = bf2f((U16)(raw.y & 0xffff)), f3 = bf2f((U16)(raw.y >> 16));
  float s = f0 + f1 + f2 + f3;
  float q = f0 * f0 + f1 * f1 + f2 * f2 + f3 * f3;
  for (int m = 1; m < 64; m <<= 1) { s += __shfl_xor(s, m); q += __shfl_xor(q, m); }
  __shared__ float ss[2], qq[2];
  if ((tid & 63) == 0) { ss[tid >> 6] = s; qq[tid >> 6] = q; }
  __syncthreads();
  s = ss[0] + ss[1]; q = qq[0] + qq[1];
  float mu = s * (1.f / 512.f);
  float var = q * (1.f / 512.f) - mu * mu;
  float rs = rsqrtf(var + 1e-5f);
  int j0 = tid * 4;
  unsigned c0 = f2bf((f0 - mu) * rs * w[j0] + bb[j0]);
  unsigned c1 = f2bf((f1 - mu) * rs * w[j0 + 1] + bb[j0 + 1]);
  unsigned c2 = f2bf((f2 - mu) * rs * w[j0 + 2] + bb[j0 + 2]);
  unsigned c3 = f2bf((f3 - mu) * rs * w[j0 + 3] + bb[j0 + 3]);
  uint2 o; o.x = c0 | (c1 << 16); o.y = c2 | (c3 << 16);
  *reinterpret_cast<uint2*>(xo + (size_t)row * 512 + j0) = o;
}

// ---------- tok partial column sums (for mean over L), deterministic ----------
__global__ __launch_bounds__(256) void tokpart_kernel(const U16* __restrict__ tok,
                                                      float* __restrict__ part) {
  int b = blockIdx.x, j = blockIdx.y * 256 + threadIdx.x, z = blockIdx.z;
  float s = 0.f;
  int l0 = z * 256;
  for (int l = l0; l < l0 + 256; ++l)
    s += bf2f(tok[((size_t)b * Lsz + l) * 512 + j]);
  part[(z * 8 + b) * 512 + j] = s;
}

// ---------- dt / dA precompute ----------
__global__ __launch_bounds__(256) void dt_kernel(const U16* __restrict__ zx,
                                                 const float* __restrict__ dt_bias,
                                                 const float* __restrict__ A_log,
                                                 float* __restrict__ dtf,
                                                 float* __restrict__ dAf) {
  int idx = blockIdx.x * 256 + threadIdx.x;  // 32768*32
  int row = idx >> 5, hh = idx & 31;
  float raw = bf2f(zx[(size_t)row * D_PROJ + 2176 + hh]) + dt_bias[hh];
  float dt = (raw > 20.f) ? raw : log1pf(__expf(raw));
  float A = -__expf(A_log[hh]);
  dtf[idx] = dt;
  dAf[idx] = __expf(dt * A);
}

// ---------- causal depthwise conv K=4 + silu; split xh / Bm / Cm ----------
__global__ __launch_bounds__(384) void conv_kernel(const U16* __restrict__ zx,
                                                   const float* __restrict__ cw,
                                                   const float* __restrict__ cb,
                                                   U16* __restrict__ xh,
                                                   U16* __restrict__ Bmo,
                                                   U16* __restrict__ Cmo) {
  int row = blockIdx.x;
  int c = blockIdx.y * 384 + threadIdx.x;
  int l = row & (Lsz - 1);
  float acc = cb[c];
  const float* w = cw + c * 4;
  #pragma unroll
  for (int k = 0; k < 4; ++k) {
    int lr = l + k - 3;
    if (lr >= 0)
      acc += bf2f(zx[(size_t)(row + k - 3) * D_PROJ + D_INNER + c]) * w[k];
  }
  float sig = 1.f / (1.f + __expf(-acc));
  U16 o = f2bf(acc * sig);
  if (c < D_INNER) xh[(size_t)row * D_INNER + c] = o;
  else if (c < D_INNER + 64) Bmo[(size_t)row * 64 + (c - D_INNER)] = o;
  else Cmo[(size_t)row * 64 + (c - D_INNER - 64)] = o;
}

// ---------- sequential SSM scan, one (b,h) per block; fused gate + mean ----------
__global__ __launch_bounds__(256) void scan_kernel(const U16* __restrict__ xh,
                                                   const U16* __restrict__ Bm,
                                                   const U16* __restrict__ Cm,
                                                   const U16* __restrict__ zx,
                                                   const float* __restrict__ dtf,
                                                   const float* __restrict__ dAf,
                                                   const float* __restrict__ Dp,
                                                   float* __restrict__ yymean) {
  const int b = blockIdx.x >> 5, hh = blockIdx.x & 31;
  const int tid = threadIdx.x;
  const int p = tid >> 3, g = tid & 7;   // thread owns state h[p][8g..8g+8)
  const int lane = tid & 63, wid = tid >> 6;
  __shared__ alignas(16) U16 Bsm[64 * 64];
  __shared__ alignas(16) U16 Csm[64 * 64];
  __shared__ alignas(16) U16 xsm[64 * 32];
  __shared__ alignas(16) U16 zsm[64 * 32];
  __shared__ float2 ads[64];
  float hst[8] = {};
  float ymacc = 0.f;
  const float Dh = Dp[hh];
  const size_t rowbase = (size_t)b * Lsz;

  for (int c0 = 0; c0 < Lsz; c0 += 64) {
    __syncthreads();
    {
      const U16* gB = Bm + (rowbase + c0) * 64;
      const U16* gC = Cm + (rowbase + c0) * 64;
      int qb = wid * 64;
      gload_lds16(gB + (size_t)(qb + lane) * 8, &Bsm[qb * 8]);
      gload_lds16(gB + (size_t)(qb + 256 + lane) * 8, &Bsm[(qb + 256) * 8]);
      gload_lds16(gC + (size_t)(qb + lane) * 8, &Csm[qb * 8]);
      gload_lds16(gC + (size_t)(qb + 256 + lane) * 8, &Csm[(qb + 256) * 8]);
      int q = qb + lane;  // 0..255 ; row t=q>>2, sub-chunk q&3
      gload_lds16(xh + (rowbase + c0 + (q >> 2)) * (size_t)D_INNER + hh * 32 + (q & 3) * 8,
                  &xsm[qb * 8]);
      gload_lds16(zx + (rowbase + c0 + (q >> 2)) * (size_t)D_PROJ + hh * 32 + (q & 3) * 8,
                  &zsm[qb * 8]);
    }
    if (tid < 64)
      ads[tid] = make_float2(dAf[(rowbase + c0 + tid) * 32 + hh],
                             dtf[(rowbase + c0 + tid) * 32 + hh]);
    __syncthreads();
    #pragma unroll 4
    for (int t = 0; t < 64; ++t) {
      float2 ad = ads[t];
      float xv = bf2f(xsm[t * 32 + p]);
      float zz = bf2f(zsm[t * 32 + p]);
      float coef = ad.y * xv;
      short8 braw = *reinterpret_cast<const short8*>(&Bsm[t * 64 + g * 8]);
      short8 craw = *reinterpret_cast<const short8*>(&Csm[t * 64 + g * 8]);
      float y0 = 0.f, y1 = 0.f;
      #pragma unroll
      for (int i = 0; i < 8; ++i) {
        float bv = bf2f((U16)braw[i]);
        float cv = bf2f((U16)craw[i]);
        hst[i] = fmaf(hst[i], ad.x, coef * bv);
        if (i & 1) y1 = fmaf(hst[i], cv, y1);
        else y0 = fmaf(hst[i], cv, y0);
      }
      float ys = y0 + y1;
      ys += __shfl_xor(ys, 1);
      ys += __shfl_xor(ys, 2);
      ys += __shfl_xor(ys, 4);
      if (g == 0) {
        float yv = ys + Dh * xv;
        float sig = 1.f / (1.f + __expf(-zz));
        ymacc += yv * (zz * sig);
      }
    }
  }
  if (g == 0) yymean[b * D_INNER + hh * 32 + p] = ymacc;  // sum over l
}

// ---------- folded epilogue: m2 = tokmean/L + (yysum/L) @ W_blk + b_blk ----------
__global__ __launch_bounds__(128) void final1_kernel(const float* __restrict__ tokpart,
                                                     const float* __restrict__ yysum,
                                                     const float* __restrict__ Wb,
                                                     const float* __restrict__ bb,
                                                     float* __restrict__ m2) {
  int b = blockIdx.x, j = blockIdx.y * 128 + threadIdx.x;
  float tm = 0.f;
  #pragma unroll
  for (int z = 0; z < 16; ++z) tm += tokpart[(z * 8 + b) * 512 + j];
  float s = 0.f;
  for (int d = 0; d < 1024; ++d) s += yysum[b * 1024 + d] * Wb[(size_t)d * 512 + j];
  m2[b * 512 + j] = (tm + s) * (1.f / (float)Lsz) + bb[j];
}

// ---------- out = m2 @ W_out + b_out ----------
__global__ __launch_bounds__(256) void final2_kernel(const float* __restrict__ m2,
                                                     const float* __restrict__ Wo,
                                                     const float* __restrict__ bo,
                                                     float* __restrict__ out) {
  int b = blockIdx.x, o = blockIdx.y * 256 + threadIdx.x;
  float s = 0.f;
  for (int j = 0; j < 512; ++j) s += m2[b * 512 + j] * Wo[(size_t)j * 1024 + o];
  out[b * 1024 + o] = s + bo[o];
}

extern "C" void kernel_launch(void* const* d_in, const int* in_sizes, int n_in,
                              void* d_out, int out_size, void* d_ws, size_t ws_size,
                              hipStream_t stream) {
  const float* image = (const float*)d_in[0];
  const float* text = (const float*)d_in[1];
  const float* W_in = (const float*)d_in[2];
  const float* b_in = (const float*)d_in[3];
  const float* W_txt = (const float*)d_in[4];
  const float* b_txt = (const float*)d_in[5];
  const float* norm_w = (const float*)d_in[6];
  const float* norm_b = (const float*)d_in[7];
  const float* W_zx = (const float*)d_in[8];
  const float* b_zx = (const float*)d_in[9];
  const float* conv_w = (const float*)d_in[10];
  const float* conv_b = (const float*)d_in[11];
  const float* dt_bias = (const float*)d_in[12];
  const float* A_log = (const float*)d_in[13];
  const float* Dp = (const float*)d_in[14];
  const float* W_blk = (const float*)d_in[15];
  const float* b_blk = (const float*)d_in[16];
  const float* W_out = (const float*)d_in[17];
  const float* b_out = (const float*)d_in[18];
  float* out = (float*)d_out;

  char* ws = (char*)d_ws;
  size_t off = 0;
  auto take = [&](size_t bytes) {
    char* p = ws + off;
    off = (off + bytes + 255) & ~(size_t)255;
    return p;
  };
  U16* img_bf = (U16*)take((size_t)MROWS * HID * 2);
  U16* wt_in = (U16*)take((size_t)DIMV * HID * 2);
  U16* wt_zx = (U16*)take((size_t)D_PROJ_PAD * DIMV * 2);
  U16* tok_bf = (U16*)take((size_t)MROWS * DIMV * 2);
  U16* x_bf = (U16*)take((size_t)MROWS * DIMV * 2);
  U16* zx_bf = (U16*)take((size_t)MROWS * D_PROJ * 2);
  U16* xh_bf = (U16*)take((size_t)MROWS * D_INNER * 2);
  U16* bm_bf = (U16*)take((size_t)MROWS * 64 * 2);
  U16* cm_bf = (U16*)take((size_t)MROWS * 64 * 2);
  float* dtf = (float*)take((size_t)MROWS * 32 * 4);
  float* dAf = (float*)take((size_t)MROWS * 32 * 4);
  float* txtf = (float*)take(8 * 512 * 4);
  float* tokpart = (float*)take(16 * 8 * 512 * 4);
  float* yysum = (float*)take(8 * 1024 * 4);
  float* m2 = (float*)take(8 * 512 * 4);

  // prep
  txt_kernel<<<8, 512, 0, stream>>>(text, W_txt, b_txt, txtf);
  cvt_f2b_kernel<<<(MROWS * HID / 4 + 255) / 256, 256, 0, stream>>>(image, img_bf, MROWS * HID / 4);
  transpose_cvt_kernel<<<dim3(DIMV / 32, HID / 32), dim3(32, 8), 0, stream>>>(W_in, wt_in, HID, DIMV, DIMV);
  transpose_cvt_kernel<<<dim3(D_PROJ_PAD / 32, DIMV / 32), dim3(32, 8), 0, stream>>>(W_zx, wt_zx, DIMV, D_PROJ, D_PROJ_PAD);

  // GEMM1: tok = image @ W_in + b_in + txt[b]
  gemm_kernel<1><<<dim3(MROWS / 128, DIMV / 128), 256, 0, stream>>>(img_bf, wt_in, tok_bf, b_in, txtf, MROWS, HID, DIMV);
  tokpart_kernel<<<dim3(8, 2, 16), 256, 0, stream>>>(tok_bf, tokpart);
  ln_kernel<<<MROWS, 128, 0, stream>>>(tok_bf, x_bf, norm_w, norm_b);

  // GEMM2: zxbcdt = x @ W_zxbcdt + b
  gemm_kernel<0><<<dim3(MROWS / 128, D_PROJ_PAD / 128), 256, 0, stream>>>(x_bf, wt_zx, zx_bf, b_zx, nullptr, MROWS, DIMV, D_PROJ);

  dt_kernel<<<MROWS * 32 / 256, 256, 0, stream>>>(zx_bf, dt_bias, A_log, dtf, dAf);
  conv_kernel<<<dim3(MROWS, 3), 384, 0, stream>>>(zx_bf, conv_w, conv_b, xh_bf, bm_bf, cm_bf);

  scan_kernel<<<256, 256, 0, stream>>>(xh_bf, bm_bf, cm_bf, zx_bf, dtf, dAf, Dp, yysum);

  final1_kernel<<<dim3(8, 4), 128, 0, stream>>>(tokpart, yysum, W_blk, b_blk, m2);
  final2_kernel<<<dim3(8, 4), 256, 0, stream>>>(m2, W_out, b_out, out);
}

// Round 2
// 899.742 us; speedup vs baseline: 1.8391x; 1.8391x over previous
//
#include <hip/hip_runtime.h>

typedef unsigned short U16;
typedef __attribute__((ext_vector_type(2))) float f32x2;
typedef __attribute__((ext_vector_type(4))) float f32x4;
typedef __attribute__((ext_vector_type(8))) short short8;
typedef __attribute__((ext_vector_type(8))) __bf16 bf16x8;

#define Bsz 8
#define Lsz 4096
#define HID 1024
#define DIMV 512
#define D_INNER 1024
#define NHEADS 32
#define HEADDIM 32
#define D_STATE 64
#define CONV_DIM 1152
#define D_PROJ 2208
#define D_PROJ_PAD 2304
#define MROWS 32768
#define CL 128        // scan chunk length
#define NCH 32        // Lsz / CL
#define SS 16         // staging substage steps

__device__ __forceinline__ float bf2f(U16 u) {
  return __builtin_bit_cast(float, (unsigned)(((unsigned)u) << 16));
}
__device__ __forceinline__ U16 f2bf(float f) {
  unsigned u = __builtin_bit_cast(unsigned, f);
  return (U16)((u + 0x7FFFu + ((u >> 16) & 1u)) >> 16);
}
__device__ __forceinline__ void gload_lds16(const void* g, void* l) {
  __builtin_amdgcn_global_load_lds((const __attribute__((address_space(1))) unsigned int*)g,
                                   (__attribute__((address_space(3))) unsigned int*)l, 16, 0, 0);
}

// ---------- tiny txt GEMM ----------
__global__ __launch_bounds__(512) void txt_kernel(const float* __restrict__ text,
                                                  const float* __restrict__ Wt,
                                                  const float* __restrict__ bt,
                                                  float* __restrict__ txt) {
  int b = blockIdx.x, j = threadIdx.x;
  float s = bt[j];
  const float* tp = text + (size_t)b * 77 * 768;
  for (int k = 0; k < 768; ++k) s += tp[k] * Wt[(size_t)k * 512 + j];
  txt[b * 512 + j] = s;
}

// ---------- f32 -> bf16 bulk convert ----------
__global__ __launch_bounds__(256) void cvt_f2b_kernel(const float* __restrict__ in,
                                                      U16* __restrict__ out, int n4) {
  int i = blockIdx.x * 256 + threadIdx.x;
  if (i < n4) {
    float4 v = reinterpret_cast<const float4*>(in)[i];
    ushort4 o;
    o.x = f2bf(v.x); o.y = f2bf(v.y); o.z = f2bf(v.z); o.w = f2bf(v.w);
    reinterpret_cast<ushort4*>(out)[i] = o;
  }
}

// ---------- transpose + convert weights ----------
__global__ __launch_bounds__(256) void transpose_cvt_kernel(const float* __restrict__ in,
                                                            U16* __restrict__ out,
                                                            int K, int N, int Npad) {
  __shared__ U16 tile[32][33];
  int n0 = blockIdx.x * 32, k0 = blockIdx.y * 32;
  int tx = threadIdx.x, ty = threadIdx.y;
  #pragma unroll
  for (int i = 0; i < 4; ++i) {
    int k = k0 + ty + i * 8, n = n0 + tx;
    float v = (n < N) ? in[(size_t)k * N + n] : 0.f;
    tile[ty + i * 8][tx] = f2bf(v);
  }
  __syncthreads();
  #pragma unroll
  for (int i = 0; i < 4; ++i) {
    int n = n0 + ty + i * 8;
    out[(size_t)n * K + k0 + tx] = tile[tx][ty + i * 8];
  }
}

// ---------- bf16 MFMA GEMM (unchanged from round 1) ----------
template <int EPI>
__global__ __launch_bounds__(256) void gemm_kernel(const U16* __restrict__ A,
                                                   const U16* __restrict__ Bt,
                                                   U16* __restrict__ C,
                                                   const float* __restrict__ bias,
                                                   const float* __restrict__ txtv,
                                                   int M, int K, int Nreal) {
  __shared__ alignas(16) U16 As[128 * 64];
  __shared__ alignas(16) U16 Bs[128 * 64];
  const int tid = threadIdx.x;
  const int wid = tid >> 6, lane = tid & 63;
  const int lhi = lane >> 4, llo = lane & 15;
  const int m0 = blockIdx.x * 128;
  const int n0 = blockIdx.y * 128;
  const int wr = wid >> 1, wc = wid & 1;
  f32x4 acc[4][4] = {};

  for (int k0 = 0; k0 < K; k0 += 64) {
    __syncthreads();
    #pragma unroll
    for (int is = 0; is < 4; ++is) {
      int qbase = is * 256 + wid * 64;
      int q = qbase + lane;
      int r = q >> 3;
      int cc = (q & 7) ^ (r & 7);
      gload_lds16(A + (size_t)(m0 + r) * K + k0 + cc * 8, &As[qbase * 8]);
    }
    #pragma unroll
    for (int is = 0; is < 4; ++is) {
      int qbase = is * 256 + wid * 64;
      int q = qbase + lane;
      int r = q >> 3;
      int cc = (q & 7) ^ (r & 7);
      gload_lds16(Bt + (size_t)(n0 + r) * K + k0 + cc * 8, &Bs[qbase * 8]);
    }
    __syncthreads();
    #pragma unroll
    for (int kk = 0; kk < 64; kk += 32) {
      bf16x8 av[4], bv[4];
      #pragma unroll
      for (int i = 0; i < 4; ++i) {
        int ra = wr * 64 + i * 16 + llo;
        short8 a = *reinterpret_cast<const short8*>(
            &As[ra * 64 + ((((kk >> 3) + lhi) ^ (ra & 7)) << 3)]);
        av[i] = __builtin_bit_cast(bf16x8, a);
        int rb = wc * 64 + i * 16 + llo;
        short8 b = *reinterpret_cast<const short8*>(
            &Bs[rb * 64 + ((((kk >> 3) + lhi) ^ (rb & 7)) << 3)]);
        bv[i] = __builtin_bit_cast(bf16x8, b);
      }
      #pragma unroll
      for (int i = 0; i < 4; ++i)
        #pragma unroll
        for (int j = 0; j < 4; ++j)
          acc[i][j] = __builtin_amdgcn_mfma_f32_16x16x32_bf16(av[i], bv[j], acc[i][j], 0, 0, 0);
    }
  }
  const int b = m0 >> 12;
  #pragma unroll
  for (int i = 0; i < 4; ++i) {
    int rbase = m0 + wr * 64 + i * 16 + lhi * 4;
    #pragma unroll
    for (int j = 0; j < 4; ++j) {
      int cg = n0 + wc * 64 + j * 16 + llo;
      if (cg < Nreal) {
        float badd = bias[cg] + (EPI ? txtv[b * 512 + cg] : 0.f);
        #pragma unroll
        for (int r = 0; r < 4; ++r)
          C[(size_t)(rbase + r) * Nreal + cg] = f2bf(acc[i][j][r] + badd);
      }
    }
  }
}

// ---------- LayerNorm ----------
__global__ __launch_bounds__(128) void ln_kernel(const U16* __restrict__ tok,
                                                 U16* __restrict__ xo,
                                                 const float* __restrict__ w,
                                                 const float* __restrict__ bb) {
  int row = blockIdx.x, tid = threadIdx.x;
  const U16* rp = tok + (size_t)row * 512 + tid * 4;
  uint2 raw = *reinterpret_cast<const uint2*>(rp);
  float f0 = bf2f((U16)(raw.x & 0xffff)), f1 = bf2f((U16)(raw.x >> 16));
  float f2 = bf2f((U16)(raw.y & 0xffff)), f3 = bf2f((U16)(raw.y >> 16));
  float s = f0 + f1 + f2 + f3;
  float q = f0 * f0 + f1 * f1 + f2 * f2 + f3 * f3;
  for (int m = 1; m < 64; m <<= 1) { s += __shfl_xor(s, m); q += __shfl_xor(q, m); }
  __shared__ float ss[2], qq[2];
  if ((tid & 63) == 0) { ss[tid >> 6] = s; qq[tid >> 6] = q; }
  __syncthreads();
  s = ss[0] + ss[1]; q = qq[0] + qq[1];
  float mu = s * (1.f / 512.f);
  float var = q * (1.f / 512.f) - mu * mu;
  float rs = rsqrtf(var + 1e-5f);
  int j0 = tid * 4;
  unsigned c0 = f2bf((f0 - mu) * rs * w[j0] + bb[j0]);
  unsigned c1 = f2bf((f1 - mu) * rs * w[j0 + 1] + bb[j0 + 1]);
  unsigned c2 = f2bf((f2 - mu) * rs * w[j0 + 2] + bb[j0 + 2]);
  unsigned c3 = f2bf((f3 - mu) * rs * w[j0 + 3] + bb[j0 + 3]);
  uint2 o; o.x = c0 | (c1 << 16); o.y = c2 | (c3 << 16);
  *reinterpret_cast<uint2*>(xo + (size_t)row * 512 + j0) = o;
}

// ---------- tok partial column sums ----------
__global__ __launch_bounds__(256) void tokpart_kernel(const U16* __restrict__ tok,
                                                      float* __restrict__ part) {
  int b = blockIdx.x, j = blockIdx.y * 256 + threadIdx.x, z = blockIdx.z;
  float s = 0.f;
  int l0 = z * 256;
  for (int l = l0; l < l0 + 256; ++l)
    s += bf2f(tok[((size_t)b * Lsz + l) * 512 + j]);
  part[(z * 8 + b) * 512 + j] = s;
}

// ---------- dt / dA precompute ----------
__global__ __launch_bounds__(256) void dt_kernel(const U16* __restrict__ zx,
                                                 const float* __restrict__ dt_bias,
                                                 const float* __restrict__ A_log,
                                                 float* __restrict__ dtf,
                                                 float* __restrict__ dAf) {
  int idx = blockIdx.x * 256 + threadIdx.x;
  int row = idx >> 5, hh = idx & 31;
  float raw = bf2f(zx[(size_t)row * D_PROJ + 2176 + hh]) + dt_bias[hh];
  float dt = (raw > 20.f) ? raw : log1pf(__expf(raw));
  float A = -__expf(A_log[hh]);
  dtf[idx] = dt;
  dAf[idx] = __expf(dt * A);
}

// ---------- causal depthwise conv K=4 + silu ----------
__global__ __launch_bounds__(384) void conv_kernel(const U16* __restrict__ zx,
                                                   const float* __restrict__ cw,
                                                   const float* __restrict__ cb,
                                                   U16* __restrict__ xh,
                                                   U16* __restrict__ Bmo,
                                                   U16* __restrict__ Cmo) {
  int row = blockIdx.x;
  int c = blockIdx.y * 384 + threadIdx.x;
  int l = row & (Lsz - 1);
  float acc = cb[c];
  const float* w = cw + c * 4;
  #pragma unroll
  for (int k = 0; k < 4; ++k) {
    int lr = l + k - 3;
    if (lr >= 0)
      acc += bf2f(zx[(size_t)(row + k - 3) * D_PROJ + D_INNER + c]) * w[k];
  }
  float sig = 1.f / (1.f + __expf(-acc));
  U16 o = f2bf(acc * sig);
  if (c < D_INNER) xh[(size_t)row * D_INNER + c] = o;
  else if (c < D_INNER + 64) Bmo[(size_t)row * 64 + (c - D_INNER)] = o;
  else Cmo[(size_t)row * 64 + (c - D_INNER - 64)] = o;
}

// ---------- chunked SSM scan: one (b,h,chunk) per 128-thread block ----------
// thread = (p = tid>>2 in [0,32), g = tid&3 owning n in [g*16, g*16+16))
// Produces per chunk: hpart (32x64), w (32x64), ylocal (32), aprod (scalar).
// B/C staged f32 in LDS with quad XOR-swizzle (sq = q ^ ((q>>3)&1)) so the
// 32B-stride b128 staging writes hit all 32 banks.
__global__ __launch_bounds__(128, 4) void scan_chunk_kernel(
    const U16* __restrict__ xh, const U16* __restrict__ Bm,
    const U16* __restrict__ Cm, const U16* __restrict__ zx,
    const float* __restrict__ dtf, const float* __restrict__ dAf,
    const float* __restrict__ Dp, float* __restrict__ hpart,
    float* __restrict__ wacc, float* __restrict__ ylocal,
    float* __restrict__ aprod) {
  const int bx = blockIdx.x;
  const int bh = bx >> 5, ci = bx & 31;
  const int b = bh >> 5, hh = bh & 31;
  const int tid = threadIdx.x;
  const int p = tid >> 2, g = tid & 3;
  const int sx = g >> 1;  // swizzle bit for this thread's quad range

  __shared__ alignas(16) float Bs[SS * 64];
  __shared__ alignas(16) float Cs[SS * 64];
  __shared__ alignas(16) float xzs[SS * 32 * 2];
  __shared__ float2 adsm[SS];

  f32x2 h2[8] = {};
  f32x2 w2[8] = {};
  float ca = 1.f, ylacc = 0.f;
  const float dterm = (g == 0) ? Dp[hh] : 0.f;
  const size_t row0 = (size_t)b * Lsz + (size_t)ci * CL;

  for (int s0 = 0; s0 < CL; s0 += SS) {
    __syncthreads();
    {
      const size_t r = row0 + s0;
      // B, C: 16 rows x 64 = 1024 bf16 each -> f32 LDS (swizzled quads)
      int e = tid * 8;
      int q0 = e >> 2, q1 = q0 + 1;
      int s0q = (q0 ^ ((q0 >> 3) & 1)) << 2;
      int s1q = (q1 ^ ((q1 >> 3) & 1)) << 2;
      short8 braw = *reinterpret_cast<const short8*>(Bm + r * 64 + e);
      short8 craw = *reinterpret_cast<const short8*>(Cm + r * 64 + e);
      f32x4 blo, bhi, clo, chi;
      #pragma unroll
      for (int i = 0; i < 4; ++i) {
        blo[i] = bf2f((U16)braw[i]); bhi[i] = bf2f((U16)braw[i + 4]);
        clo[i] = bf2f((U16)craw[i]); chi[i] = bf2f((U16)craw[i + 4]);
      }
      *reinterpret_cast<f32x4*>(&Bs[s0q]) = blo;
      *reinterpret_cast<f32x4*>(&Bs[s1q]) = bhi;
      *reinterpret_cast<f32x4*>(&Cs[s0q]) = clo;
      *reinterpret_cast<f32x4*>(&Cs[s1q]) = chi;
      // x, z interleaved per (t,p): xzs[(t*32+p)*2 + {0,1}]
      if (tid < 64) {
        int e2 = tid * 8, t = e2 >> 5, c = e2 & 31;
        short8 xr = *reinterpret_cast<const short8*>(
            xh + (r + t) * (size_t)D_INNER + hh * 32 + c);
        #pragma unroll
        for (int j = 0; j < 8; ++j) xzs[(t * 32 + c + j) * 2] = bf2f((U16)xr[j]);
      } else {
        int e2 = (tid - 64) * 8, t = e2 >> 5, c = e2 & 31;
        short8 zr = *reinterpret_cast<const short8*>(
            zx + (r + t) * (size_t)D_PROJ + hh * 32 + c);
        #pragma unroll
        for (int j = 0; j < 8; ++j) xzs[(t * 32 + c + j) * 2 + 1] = bf2f((U16)zr[j]);
      }
      if (tid < SS)
        adsm[tid] = make_float2(dAf[(r + tid) * 32 + hh], dtf[(r + tid) * 32 + hh]);
    }
    __syncthreads();

    for (int t = 0; t < SS; ++t) {
      float2 ad = adsm[t];
      f32x2 xz = *reinterpret_cast<const f32x2*>(&xzs[(t * 32 + p) * 2]);
      const float* brow = &Bs[t * 64 + g * 16];
      const float* crow = &Cs[t * 64 + g * 16];
      f32x4 bq[4], cq[4];
      #pragma unroll
      for (int k = 0; k < 4; ++k) {
        int kk = ((k ^ sx) << 2);
        bq[k] = *reinterpret_cast<const f32x4*>(brow + kk);
        cq[k] = *reinterpret_cast<const f32x4*>(crow + kk);
      }
      ca *= ad.x;
      float coef = ad.y * xz[0];
      float ez = __expf(-xz[1]);
      float gz = xz[1] / (1.f + ez);
      float gzca = gz * ca;
      f32x2 adx2 = {ad.x, ad.x};
      f32x2 coef2 = {coef, coef};
      f32x2 gzca2 = {gzca, gzca};
      f32x2 yp[4];
      yp[0] = (f32x2){dterm * xz[0], 0.f};
      yp[1] = (f32x2){0.f, 0.f};
      yp[2] = (f32x2){0.f, 0.f};
      yp[3] = (f32x2){0.f, 0.f};
      #pragma unroll
      for (int k = 0; k < 4; ++k) {
        f32x2 bl = __builtin_shufflevector(bq[k], bq[k], 0, 1);
        f32x2 bh_ = __builtin_shufflevector(bq[k], bq[k], 2, 3);
        f32x2 cl = __builtin_shufflevector(cq[k], cq[k], 0, 1);
        f32x2 ch_ = __builtin_shufflevector(cq[k], cq[k], 2, 3);
        h2[2 * k] = h2[2 * k] * adx2 + coef2 * bl;
        h2[2 * k + 1] = h2[2 * k + 1] * adx2 + coef2 * bh_;
        yp[k] = yp[k] + h2[2 * k] * cl + h2[2 * k + 1] * ch_;
        w2[2 * k] = w2[2 * k] + gzca2 * cl;
        w2[2 * k + 1] = w2[2 * k + 1] + gzca2 * ch_;
      }
      f32x2 yps = (yp[0] + yp[1]) + (yp[2] + yp[3]);
      ylacc = fmaf(gz, yps[0] + yps[1], ylacc);
    }
  }

  // epilogue
  {
    size_t base = (size_t)bx * 2048 + (size_t)tid * 16;  // p*64 + g*16
    #pragma unroll
    for (int k = 0; k < 4; ++k) {
      f32x4 hv = __builtin_shufflevector(h2[2 * k], h2[2 * k + 1], 0, 1, 2, 3);
      f32x4 wv = __builtin_shufflevector(w2[2 * k], w2[2 * k + 1], 0, 1, 2, 3);
      *reinterpret_cast<f32x4*>(&hpart[base + k * 4]) = hv;
      *reinterpret_cast<f32x4*>(&wacc[base + k * 4]) = wv;
    }
    ylacc += __shfl_xor(ylacc, 1);
    ylacc += __shfl_xor(ylacc, 2);
    if (g == 0) ylocal[bx * 32 + p] = ylacc;
    if (tid == 0) aprod[bx] = ca;
  }
}

// ---------- sequential combine across chunks + deferred correction ----------
__global__ __launch_bounds__(256) void scan_combine_kernel(
    const float* __restrict__ hpart, const float* __restrict__ wacc,
    const float* __restrict__ ylocal, const float* __restrict__ aprod,
    float* __restrict__ yysum) {
  const int bh = blockIdx.x, tid = threadIdx.x;
  const int p = tid >> 3, g = tid & 7;
  f32x4 hr0 = {}, hr1 = {};
  f32x4 corr4 = {};
  for (int ci = 0; ci < NCH; ++ci) {
    size_t base = ((size_t)(bh * NCH + ci)) * 2048 + (size_t)tid * 8;
    f32x4 w0 = *reinterpret_cast<const f32x4*>(wacc + base);
    f32x4 w1 = *reinterpret_cast<const f32x4*>(wacc + base + 4);
    f32x4 p0 = *reinterpret_cast<const f32x4*>(hpart + base);
    f32x4 p1 = *reinterpret_cast<const f32x4*>(hpart + base + 4);
    float ap = aprod[bh * NCH + ci];
    corr4 = corr4 + hr0 * w0 + hr1 * w1;
    f32x4 ap4 = {ap, ap, ap, ap};
    hr0 = hr0 * ap4 + p0;
    hr1 = hr1 * ap4 + p1;
  }
  float corr = (corr4[0] + corr4[1]) + (corr4[2] + corr4[3]);
  corr += __shfl_xor(corr, 1);
  corr += __shfl_xor(corr, 2);
  corr += __shfl_xor(corr, 4);
  if (g == 0) {
    float yl = 0.f;
    for (int ci = 0; ci < NCH; ++ci) yl += ylocal[(bh * NCH + ci) * 32 + p];
    yysum[(bh >> 5) * 1024 + (bh & 31) * 32 + p] = yl + corr;
  }
}

// ---------- folded epilogue ----------
__global__ __launch_bounds__(128) void final1_kernel(const float* __restrict__ tokpart,
                                                     const float* __restrict__ yysum,
                                                     const float* __restrict__ Wb,
                                                     const float* __restrict__ bb,
                                                     float* __restrict__ m2) {
  int b = blockIdx.x, j = blockIdx.y * 128 + threadIdx.x;
  float tm = 0.f;
  #pragma unroll
  for (int z = 0; z < 16; ++z) tm += tokpart[(z * 8 + b) * 512 + j];
  float s = 0.f;
  for (int d = 0; d < 1024; ++d) s += yysum[b * 1024 + d] * Wb[(size_t)d * 512 + j];
  m2[b * 512 + j] = (tm + s) * (1.f / (float)Lsz) + bb[j];
}

__global__ __launch_bounds__(256) void final2_kernel(const float* __restrict__ m2,
                                                     const float* __restrict__ Wo,
                                                     const float* __restrict__ bo,
                                                     float* __restrict__ out) {
  int b = blockIdx.x, o = blockIdx.y * 256 + threadIdx.x;
  float s = 0.f;
  for (int j = 0; j < 512; ++j) s += m2[b * 512 + j] * Wo[(size_t)j * 1024 + o];
  out[b * 1024 + o] = s + bo[o];
}

extern "C" void kernel_launch(void* const* d_in, const int* in_sizes, int n_in,
                              void* d_out, int out_size, void* d_ws, size_t ws_size,
                              hipStream_t stream) {
  const float* image = (const float*)d_in[0];
  const float* text = (const float*)d_in[1];
  const float* W_in = (const float*)d_in[2];
  const float* b_in = (const float*)d_in[3];
  const float* W_txt = (const float*)d_in[4];
  const float* b_txt = (const float*)d_in[5];
  const float* norm_w = (const float*)d_in[6];
  const float* norm_b = (const float*)d_in[7];
  const float* W_zx = (const float*)d_in[8];
  const float* b_zx = (const float*)d_in[9];
  const float* conv_w = (const float*)d_in[10];
  const float* conv_b = (const float*)d_in[11];
  const float* dt_bias = (const float*)d_in[12];
  const float* A_log = (const float*)d_in[13];
  const float* Dp = (const float*)d_in[14];
  const float* W_blk = (const float*)d_in[15];
  const float* b_blk = (const float*)d_in[16];
  const float* W_out = (const float*)d_in[17];
  const float* b_out = (const float*)d_in[18];
  float* out = (float*)d_out;

  char* ws = (char*)d_ws;
  size_t off = 0;
  auto take = [&](size_t bytes) {
    char* p = ws + off;
    off = (off + bytes + 255) & ~(size_t)255;
    return p;
  };
  U16* img_bf = (U16*)take((size_t)MROWS * HID * 2);      // 64 MB, dead after GEMM1
  U16* wt_in = (U16*)take((size_t)DIMV * HID * 2);
  U16* wt_zx = (U16*)take((size_t)D_PROJ_PAD * DIMV * 2);
  U16* tok_bf = (U16*)take((size_t)MROWS * DIMV * 2);     // 32 MB, dead after GEMM2/tokpart
  U16* x_bf = (U16*)take((size_t)MROWS * DIMV * 2);       // 32 MB, dead after GEMM2 (contiguous w/ tok_bf)
  U16* zx_bf = (U16*)take((size_t)MROWS * D_PROJ * 2);
  U16* xh_bf = (U16*)take((size_t)MROWS * D_INNER * 2);
  U16* bm_bf = (U16*)take((size_t)MROWS * 64 * 2);
  U16* cm_bf = (U16*)take((size_t)MROWS * 64 * 2);
  float* dtf = (float*)take((size_t)MROWS * 32 * 4);
  float* dAf = (float*)take((size_t)MROWS * 32 * 4);
  float* txtf = (float*)take(8 * 512 * 4);
  float* tokpart = (float*)take(16 * 8 * 512 * 4);
  float* yysum = (float*)take(8 * 1024 * 4);
  float* m2 = (float*)take(8 * 512 * 4);
  float* ylocal = (float*)take((size_t)256 * NCH * 32 * 4);
  float* aprod = (float*)take((size_t)256 * NCH * 4);
  // big scan scratch overlays dead buffers (exact-size fits):
  float* hpart = (float*)img_bf;   // 256*32*2048*4 = 64 MB == img_bf
  float* wacc = (float*)tok_bf;    // 64 MB spans tok_bf + x_bf (contiguous)

  txt_kernel<<<8, 512, 0, stream>>>(text, W_txt, b_txt, txtf);
  cvt_f2b_kernel<<<(MROWS * HID / 4 + 255) / 256, 256, 0, stream>>>(image, img_bf, MROWS * HID / 4);
  transpose_cvt_kernel<<<dim3(DIMV / 32, HID / 32), dim3(32, 8), 0, stream>>>(W_in, wt_in, HID, DIMV, DIMV);
  transpose_cvt_kernel<<<dim3(D_PROJ_PAD / 32, DIMV / 32), dim3(32, 8), 0, stream>>>(W_zx, wt_zx, DIMV, D_PROJ, D_PROJ_PAD);

  gemm_kernel<1><<<dim3(MROWS / 128, DIMV / 128), 256, 0, stream>>>(img_bf, wt_in, tok_bf, b_in, txtf, MROWS, HID, DIMV);
  tokpart_kernel<<<dim3(8, 2, 16), 256, 0, stream>>>(tok_bf, tokpart);
  ln_kernel<<<MROWS, 128, 0, stream>>>(tok_bf, x_bf, norm_w, norm_b);

  gemm_kernel<0><<<dim3(MROWS / 128, D_PROJ_PAD / 128), 256, 0, stream>>>(x_bf, wt_zx, zx_bf, b_zx, nullptr, MROWS, DIMV, D_PROJ);

  dt_kernel<<<MROWS * 32 / 256, 256, 0, stream>>>(zx_bf, dt_bias, A_log, dtf, dAf);
  conv_kernel<<<dim3(MROWS, 3), 384, 0, stream>>>(zx_bf, conv_w, conv_b, xh_bf, bm_bf, cm_bf);

  scan_chunk_kernel<<<256 * NCH, 128, 0, stream>>>(xh_bf, bm_bf, cm_bf, zx_bf, dtf, dAf, Dp,
                                                   hpart, wacc, ylocal, aprod);
  scan_combine_kernel<<<256, 256, 0, stream>>>(hpart, wacc, ylocal, aprod, yysum);

  final1_kernel<<<dim3(8, 4), 128, 0, stream>>>(tokpart, yysum, W_blk, b_blk, m2);
  final2_kernel<<<dim3(8, 4), 256, 0, stream>>>(m2, W_out, b_out, out);
}

// Round 3
// 741.467 us; speedup vs baseline: 2.2316x; 1.2135x over previous
//
#include <hip/hip_runtime.h>

typedef unsigned short U16;
typedef __attribute__((ext_vector_type(2))) float f32x2;
typedef __attribute__((ext_vector_type(4))) float f32x4;
typedef __attribute__((ext_vector_type(8))) short short8;
typedef __attribute__((ext_vector_type(8))) __bf16 bf16x8;

#define Bsz 8
#define Lsz 4096
#define HID 1024
#define DIMV 512
#define D_INNER 1024
#define NHEADS 32
#define HEADDIM 32
#define D_STATE 64
#define CONV_DIM 1152
#define D_PROJ 2208
#define D_PROJ_PAD 2304
#define MROWS 32768
#define CL 256        // scan chunk length
#define NCH 16        // Lsz / CL
#define SS 16         // staging substage steps

__device__ __forceinline__ float bf2f(U16 u) {
  return __builtin_bit_cast(float, (unsigned)(((unsigned)u) << 16));
}
__device__ __forceinline__ U16 f2bf(float f) {
  unsigned u = __builtin_bit_cast(unsigned, f);
  return (U16)((u + 0x7FFFu + ((u >> 16) & 1u)) >> 16);
}
__device__ __forceinline__ void gload_lds16(const void* g, void* l) {
  __builtin_amdgcn_global_load_lds((const __attribute__((address_space(1))) unsigned int*)g,
                                   (__attribute__((address_space(3))) unsigned int*)l, 16, 0, 0);
}

// ---------- tiny txt GEMM ----------
__global__ __launch_bounds__(512) void txt_kernel(const float* __restrict__ text,
                                                  const float* __restrict__ Wt,
                                                  const float* __restrict__ bt,
                                                  float* __restrict__ txt) {
  int b = blockIdx.x, j = threadIdx.x;
  float s = bt[j];
  const float* tp = text + (size_t)b * 77 * 768;
  for (int k = 0; k < 768; ++k) s += tp[k] * Wt[(size_t)k * 512 + j];
  txt[b * 512 + j] = s;
}

// ---------- f32 -> bf16 bulk convert ----------
__global__ __launch_bounds__(256) void cvt_f2b_kernel(const float* __restrict__ in,
                                                      U16* __restrict__ out, int n4) {
  int i = blockIdx.x * 256 + threadIdx.x;
  if (i < n4) {
    float4 v = reinterpret_cast<const float4*>(in)[i];
    ushort4 o;
    o.x = f2bf(v.x); o.y = f2bf(v.y); o.z = f2bf(v.z); o.w = f2bf(v.w);
    reinterpret_cast<ushort4*>(out)[i] = o;
  }
}

// ---------- transpose + convert weights ----------
__global__ __launch_bounds__(256) void transpose_cvt_kernel(const float* __restrict__ in,
                                                            U16* __restrict__ out,
                                                            int K, int N, int Npad) {
  __shared__ U16 tile[32][33];
  int n0 = blockIdx.x * 32, k0 = blockIdx.y * 32;
  int tx = threadIdx.x, ty = threadIdx.y;
  #pragma unroll
  for (int i = 0; i < 4; ++i) {
    int k = k0 + ty + i * 8, n = n0 + tx;
    float v = (n < N) ? in[(size_t)k * N + n] : 0.f;
    tile[ty + i * 8][tx] = f2bf(v);
  }
  __syncthreads();
  #pragma unroll
  for (int i = 0; i < 4; ++i) {
    int n = n0 + ty + i * 8;
    out[(size_t)n * K + k0 + tx] = tile[tx][ty + i * 8];
  }
}

// ---------- bf16 MFMA GEMM (unchanged) ----------
template <int EPI>
__global__ __launch_bounds__(256) void gemm_kernel(const U16* __restrict__ A,
                                                   const U16* __restrict__ Bt,
                                                   U16* __restrict__ C,
                                                   const float* __restrict__ bias,
                                                   const float* __restrict__ txtv,
                                                   int M, int K, int Nreal) {
  __shared__ alignas(16) U16 As[128 * 64];
  __shared__ alignas(16) U16 Bs[128 * 64];
  const int tid = threadIdx.x;
  const int wid = tid >> 6, lane = tid & 63;
  const int lhi = lane >> 4, llo = lane & 15;
  const int m0 = blockIdx.x * 128;
  const int n0 = blockIdx.y * 128;
  const int wr = wid >> 1, wc = wid & 1;
  f32x4 acc[4][4] = {};

  for (int k0 = 0; k0 < K; k0 += 64) {
    __syncthreads();
    #pragma unroll
    for (int is = 0; is < 4; ++is) {
      int qbase = is * 256 + wid * 64;
      int q = qbase + lane;
      int r = q >> 3;
      int cc = (q & 7) ^ (r & 7);
      gload_lds16(A + (size_t)(m0 + r) * K + k0 + cc * 8, &As[qbase * 8]);
    }
    #pragma unroll
    for (int is = 0; is < 4; ++is) {
      int qbase = is * 256 + wid * 64;
      int q = qbase + lane;
      int r = q >> 3;
      int cc = (q & 7) ^ (r & 7);
      gload_lds16(Bt + (size_t)(n0 + r) * K + k0 + cc * 8, &Bs[qbase * 8]);
    }
    __syncthreads();
    #pragma unroll
    for (int kk = 0; kk < 64; kk += 32) {
      bf16x8 av[4], bv[4];
      #pragma unroll
      for (int i = 0; i < 4; ++i) {
        int ra = wr * 64 + i * 16 + llo;
        short8 a = *reinterpret_cast<const short8*>(
            &As[ra * 64 + ((((kk >> 3) + lhi) ^ (ra & 7)) << 3)]);
        av[i] = __builtin_bit_cast(bf16x8, a);
        int rb = wc * 64 + i * 16 + llo;
        short8 b = *reinterpret_cast<const short8*>(
            &Bs[rb * 64 + ((((kk >> 3) + lhi) ^ (rb & 7)) << 3)]);
        bv[i] = __builtin_bit_cast(bf16x8, b);
      }
      #pragma unroll
      for (int i = 0; i < 4; ++i)
        #pragma unroll
        for (int j = 0; j < 4; ++j)
          acc[i][j] = __builtin_amdgcn_mfma_f32_16x16x32_bf16(av[i], bv[j], acc[i][j], 0, 0, 0);
    }
  }
  const int b = m0 >> 12;
  #pragma unroll
  for (int i = 0; i < 4; ++i) {
    int rbase = m0 + wr * 64 + i * 16 + lhi * 4;
    #pragma unroll
    for (int j = 0; j < 4; ++j) {
      int cg = n0 + wc * 64 + j * 16 + llo;
      if (cg < Nreal) {
        float badd = bias[cg] + (EPI ? txtv[b * 512 + cg] : 0.f);
        #pragma unroll
        for (int r = 0; r < 4; ++r)
          C[(size_t)(rbase + r) * Nreal + cg] = f2bf(acc[i][j][r] + badd);
      }
    }
  }
}

// ---------- LayerNorm ----------
__global__ __launch_bounds__(128) void ln_kernel(const U16* __restrict__ tok,
                                                 U16* __restrict__ xo,
                                                 const float* __restrict__ w,
                                                 const float* __restrict__ bb) {
  int row = blockIdx.x, tid = threadIdx.x;
  const U16* rp = tok + (size_t)row * 512 + tid * 4;
  uint2 raw = *reinterpret_cast<const uint2*>(rp);
  float f0 = bf2f((U16)(raw.x & 0xffff)), f1 = bf2f((U16)(raw.x >> 16));
  float f2 = bf2f((U16)(raw.y & 0xffff)), f3 = bf2f((U16)(raw.y >> 16));
  float s = f0 + f1 + f2 + f3;
  float q = f0 * f0 + f1 * f1 + f2 * f2 + f3 * f3;
  for (int m = 1; m < 64; m <<= 1) { s += __shfl_xor(s, m); q += __shfl_xor(q, m); }
  __shared__ float ss[2], qq[2];
  if ((tid & 63) == 0) { ss[tid >> 6] = s; qq[tid >> 6] = q; }
  __syncthreads();
  s = ss[0] + ss[1]; q = qq[0] + qq[1];
  float mu = s * (1.f / 512.f);
  float var = q * (1.f / 512.f) - mu * mu;
  float rs = rsqrtf(var + 1e-5f);
  int j0 = tid * 4;
  unsigned c0 = f2bf((f0 - mu) * rs * w[j0] + bb[j0]);
  unsigned c1 = f2bf((f1 - mu) * rs * w[j0 + 1] + bb[j0 + 1]);
  unsigned c2 = f2bf((f2 - mu) * rs * w[j0 + 2] + bb[j0 + 2]);
  unsigned c3 = f2bf((f3 - mu) * rs * w[j0 + 3] + bb[j0 + 3]);
  uint2 o; o.x = c0 | (c1 << 16); o.y = c2 | (c3 << 16);
  *reinterpret_cast<uint2*>(xo + (size_t)row * 512 + j0) = o;
}

// ---------- tok partial column sums ----------
__global__ __launch_bounds__(256) void tokpart_kernel(const U16* __restrict__ tok,
                                                      float* __restrict__ part) {
  int b = blockIdx.x, j = blockIdx.y * 256 + threadIdx.x, z = blockIdx.z;
  float s = 0.f;
  int l0 = z * 256;
  for (int l = l0; l < l0 + 256; ++l)
    s += bf2f(tok[((size_t)b * Lsz + l) * 512 + j]);
  part[(z * 8 + b) * 512 + j] = s;
}

// ---------- dt / dA precompute ----------
__global__ __launch_bounds__(256) void dt_kernel(const U16* __restrict__ zx,
                                                 const float* __restrict__ dt_bias,
                                                 const float* __restrict__ A_log,
                                                 float* __restrict__ dtf,
                                                 float* __restrict__ dAf) {
  int idx = blockIdx.x * 256 + threadIdx.x;
  int row = idx >> 5, hh = idx & 31;
  float raw = bf2f(zx[(size_t)row * D_PROJ + 2176 + hh]) + dt_bias[hh];
  float dt = (raw > 20.f) ? raw : log1pf(__expf(raw));
  float A = -__expf(A_log[hh]);
  dtf[idx] = dt;
  dAf[idx] = __expf(dt * A);
}

// ---------- causal depthwise conv K=4 + silu; 4 rows per thread ----------
__global__ __launch_bounds__(384) void conv_kernel(const U16* __restrict__ zx,
                                                   const float* __restrict__ cw,
                                                   const float* __restrict__ cb,
                                                   U16* __restrict__ xh,
                                                   U16* __restrict__ Bmo,
                                                   U16* __restrict__ Cmo) {
  int row0 = blockIdx.x * 4;
  int c = blockIdx.y * 384 + threadIdx.x;
  int l0 = row0 & (Lsz - 1);
  float4 w4 = *reinterpret_cast<const float4*>(cw + c * 4);
  float cbv = cb[c];
  float v[7];
  #pragma unroll
  for (int k = 0; k < 7; ++k) {
    int lr = l0 + k - 3;
    v[k] = (lr >= 0) ? bf2f(zx[(size_t)(row0 + k - 3) * D_PROJ + D_INNER + c]) : 0.f;
  }
  #pragma unroll
  for (int j = 0; j < 4; ++j) {
    float acc = cbv + v[j] * w4.x + v[j + 1] * w4.y + v[j + 2] * w4.z + v[j + 3] * w4.w;
    float sig = 1.f / (1.f + __expf(-acc));
    U16 o = f2bf(acc * sig);
    size_t row = row0 + j;
    if (c < D_INNER) xh[row * D_INNER + c] = o;
    else if (c < D_INNER + 64) Bmo[row * 64 + (c - D_INNER)] = o;
    else Cmo[row * 64 + (c - D_INNER - 64)] = o;
  }
}

// ---------- chunked SSM scan: one (b,ci,h) per 64-thread block ----------
// thread = (pg = tid>>3 owning p in [4pg,4pg+4), ng = tid&7 owning n in [8ng,8ng+8))
// B/C staged bf16 (broadcast-friendly), x / silu(z) staged f32 (swizzled).
__global__ __launch_bounds__(64, 2) void scan_chunk_kernel(
    const U16* __restrict__ xh, const U16* __restrict__ Bm,
    const U16* __restrict__ Cm, const U16* __restrict__ zx,
    const float* __restrict__ dtf, const float* __restrict__ dAf,
    const float* __restrict__ Dp, float* __restrict__ hpart,
    float* __restrict__ wacc, float* __restrict__ ylocal,
    float* __restrict__ aprod) {
  const int bx = blockIdx.x;
  const int hh = bx & 31;               // fastest -> consecutive blocks share B/C (L2 reuse)
  const int ci = (bx >> 5) & (NCH - 1);
  const int b = bx >> 9;                // 32*NCH = 512
  const int tid = threadIdx.x;
  const int pg = tid >> 3, ng = tid & 7;

  __shared__ alignas(16) U16 Bs[SS * 64];
  __shared__ alignas(16) U16 Cs[SS * 64];
  __shared__ alignas(16) float xs[SS * 32];
  __shared__ alignas(16) float gzs[SS * 32];
  __shared__ float2 ads[SS];

  f32x4 h[4][2] = {};
  f32x4 w[4][2] = {};
  f32x4 ylv[4][2] = {};
  f32x4 sdx = {};
  float ca = 1.f;
  const size_t row0 = (size_t)b * Lsz + (size_t)ci * CL;

  for (int s0 = 0; s0 < CL; s0 += SS) {
    __syncthreads();
    {
      const size_t r = row0 + s0;
      // B, C: 16 rows x 64 bf16 = 2KB contiguous each
      gload_lds16(Bm + r * 64 + tid * 8, Bs);
      gload_lds16(Bm + r * 64 + 512 + tid * 8, Bs + 512);
      gload_lds16(Cm + r * 64 + tid * 8, Cs);
      gload_lds16(Cm + r * 64 + 512 + tid * 8, Cs + 512);
      // x, silu(z): 16 rows x 32, reg-staged + converted, XOR-swizzled columns
      int t = tid >> 2, c = (tid & 3) * 8;
      int cs = c ^ ((t & 3) << 3);
      short8 xr = *reinterpret_cast<const short8*>(
          xh + (r + t) * (size_t)D_INNER + hh * 32 + c);
      short8 zr = *reinterpret_cast<const short8*>(
          zx + (r + t) * (size_t)D_PROJ + hh * 32 + c);
      f32x4 x0, x1, g0, g1;
      #pragma unroll
      for (int i = 0; i < 4; ++i) {
        x0[i] = bf2f((U16)xr[i]); x1[i] = bf2f((U16)xr[i + 4]);
        float z0 = bf2f((U16)zr[i]), z1 = bf2f((U16)zr[i + 4]);
        g0[i] = z0 / (1.f + __expf(-z0));
        g1[i] = z1 / (1.f + __expf(-z1));
      }
      *reinterpret_cast<f32x4*>(&xs[t * 32 + cs]) = x0;
      *reinterpret_cast<f32x4*>(&xs[t * 32 + cs + 4]) = x1;
      *reinterpret_cast<f32x4*>(&gzs[t * 32 + cs]) = g0;
      *reinterpret_cast<f32x4*>(&gzs[t * 32 + cs + 4]) = g1;
      if (tid < SS)
        ads[tid] = make_float2(dAf[(r + tid) * 32 + hh], dtf[(r + tid) * 32 + hh]);
    }
    __syncthreads();

    #pragma unroll 4
    for (int t = 0; t < SS; ++t) {
      float2 ad = ads[t];
      int pcs = (pg * 4) ^ ((t & 3) << 3);
      f32x4 xv = *reinterpret_cast<const f32x4*>(&xs[t * 32 + pcs]);
      f32x4 gz4 = *reinterpret_cast<const f32x4*>(&gzs[t * 32 + pcs]);
      short8 braw = *reinterpret_cast<const short8*>(&Bs[t * 64 + ng * 8]);
      short8 craw = *reinterpret_cast<const short8*>(&Cs[t * 64 + ng * 8]);
      f32x4 b0, b1, c0, c1;
      #pragma unroll
      for (int i = 0; i < 4; ++i) {
        b0[i] = bf2f((U16)braw[i]); b1[i] = bf2f((U16)braw[i + 4]);
        c0[i] = bf2f((U16)craw[i]); c1[i] = bf2f((U16)craw[i + 4]);
      }
      ca *= ad.x;
      f32x4 coef = xv * ad.y;
      f32x4 gzca = gz4 * ca;
      sdx = sdx + gz4 * xv;
      #pragma unroll
      for (int p = 0; p < 4; ++p) {
        float cp = coef[p], gp = gz4[p], wp = gzca[p];
        h[p][0] = h[p][0] * ad.x + b0 * cp;
        h[p][1] = h[p][1] * ad.x + b1 * cp;
        ylv[p][0] = ylv[p][0] + (h[p][0] * c0) * gp;
        ylv[p][1] = ylv[p][1] + (h[p][1] * c1) * gp;
        w[p][0] = w[p][0] + c0 * wp;
        w[p][1] = w[p][1] + c1 * wp;
      }
    }
  }

  // epilogue
  {
    const float Dh = Dp[hh];
    size_t base = (size_t)bx * 2048 + (size_t)(pg * 4) * 64 + ng * 8;
    #pragma unroll
    for (int p = 0; p < 4; ++p) {
      *reinterpret_cast<f32x4*>(&hpart[base + p * 64]) = h[p][0];
      *reinterpret_cast<f32x4*>(&hpart[base + p * 64 + 4]) = h[p][1];
      *reinterpret_cast<f32x4*>(&wacc[base + p * 64]) = w[p][0];
      *reinterpret_cast<f32x4*>(&wacc[base + p * 64 + 4]) = w[p][1];
    }
    float ys[4];
    #pragma unroll
    for (int p = 0; p < 4; ++p) {
      f32x4 s = ylv[p][0] + ylv[p][1];
      ys[p] = (s[0] + s[1]) + (s[2] + s[3]);
    }
    #pragma unroll
    for (int m = 1; m < 8; m <<= 1) {
      #pragma unroll
      for (int p = 0; p < 4; ++p) ys[p] += __shfl_xor(ys[p], m);
    }
    if (ng == 0) {
      #pragma unroll
      for (int p = 0; p < 4; ++p)
        ylocal[(size_t)bx * 32 + pg * 4 + p] = ys[p] + Dh * sdx[p];
    }
    if (tid == 0) aprod[bx] = ca;
  }
}

// ---------- sequential combine across chunks + deferred correction ----------
__global__ __launch_bounds__(256) void scan_combine_kernel(
    const float* __restrict__ hpart, const float* __restrict__ wacc,
    const float* __restrict__ ylocal, const float* __restrict__ aprod,
    float* __restrict__ yysum) {
  const int bh = blockIdx.x, tid = threadIdx.x;
  const int b = bh >> 5, hh = bh & 31;
  const int p = tid >> 3, g = tid & 7;
  f32x4 hr0 = {}, hr1 = {};
  f32x4 corr4 = {};
  for (int ci = 0; ci < NCH; ++ci) {
    int bx = b * (NCH * 32) + ci * 32 + hh;
    size_t base = (size_t)bx * 2048 + (size_t)tid * 8;
    f32x4 w0 = *reinterpret_cast<const f32x4*>(wacc + base);
    f32x4 w1 = *reinterpret_cast<const f32x4*>(wacc + base + 4);
    f32x4 p0 = *reinterpret_cast<const f32x4*>(hpart + base);
    f32x4 p1 = *reinterpret_cast<const f32x4*>(hpart + base + 4);
    float ap = aprod[bx];
    corr4 = corr4 + hr0 * w0 + hr1 * w1;
    hr0 = hr0 * ap + p0;
    hr1 = hr1 * ap + p1;
  }
  float corr = (corr4[0] + corr4[1]) + (corr4[2] + corr4[3]);
  corr += __shfl_xor(corr, 1);
  corr += __shfl_xor(corr, 2);
  corr += __shfl_xor(corr, 4);
  if (g == 0) {
    float yl = 0.f;
    for (int ci = 0; ci < NCH; ++ci)
      yl += ylocal[(size_t)(b * (NCH * 32) + ci * 32 + hh) * 32 + p];
    yysum[b * 1024 + hh * 32 + p] = yl + corr;
  }
}

// ---------- folded epilogue ----------
__global__ __launch_bounds__(128) void final1_kernel(const float* __restrict__ tokpart,
                                                     const float* __restrict__ yysum,
                                                     const float* __restrict__ Wb,
                                                     const float* __restrict__ bb,
                                                     float* __restrict__ m2) {
  int b = blockIdx.x, j = blockIdx.y * 128 + threadIdx.x;
  float tm = 0.f;
  #pragma unroll
  for (int z = 0; z < 16; ++z) tm += tokpart[(z * 8 + b) * 512 + j];
  float s = 0.f;
  for (int d = 0; d < 1024; ++d) s += yysum[b * 1024 + d] * Wb[(size_t)d * 512 + j];
  m2[b * 512 + j] = (tm + s) * (1.f / (float)Lsz) + bb[j];
}

__global__ __launch_bounds__(256) void final2_kernel(const float* __restrict__ m2,
                                                     const float* __restrict__ Wo,
                                                     const float* __restrict__ bo,
                                                     float* __restrict__ out) {
  int b = blockIdx.x, o = blockIdx.y * 256 + threadIdx.x;
  float s = 0.f;
  for (int j = 0; j < 512; ++j) s += m2[b * 512 + j] * Wo[(size_t)j * 1024 + o];
  out[b * 1024 + o] = s + bo[o];
}

extern "C" void kernel_launch(void* const* d_in, const int* in_sizes, int n_in,
                              void* d_out, int out_size, void* d_ws, size_t ws_size,
                              hipStream_t stream) {
  const float* image = (const float*)d_in[0];
  const float* text = (const float*)d_in[1];
  const float* W_in = (const float*)d_in[2];
  const float* b_in = (const float*)d_in[3];
  const float* W_txt = (const float*)d_in[4];
  const float* b_txt = (const float*)d_in[5];
  const float* norm_w = (const float*)d_in[6];
  const float* norm_b = (const float*)d_in[7];
  const float* W_zx = (const float*)d_in[8];
  const float* b_zx = (const float*)d_in[9];
  const float* conv_w = (const float*)d_in[10];
  const float* conv_b = (const float*)d_in[11];
  const float* dt_bias = (const float*)d_in[12];
  const float* A_log = (const float*)d_in[13];
  const float* Dp = (const float*)d_in[14];
  const float* W_blk = (const float*)d_in[15];
  const float* b_blk = (const float*)d_in[16];
  const float* W_out = (const float*)d_in[17];
  const float* b_out = (const float*)d_in[18];
  float* out = (float*)d_out;

  char* ws = (char*)d_ws;
  size_t off = 0;
  auto take = [&](size_t bytes) {
    char* p = ws + off;
    off = (off + bytes + 255) & ~(size_t)255;
    return p;
  };
  U16* img_bf = (U16*)take((size_t)MROWS * HID * 2);      // 64 MB, dead after GEMM1
  U16* wt_in = (U16*)take((size_t)DIMV * HID * 2);
  U16* wt_zx = (U16*)take((size_t)D_PROJ_PAD * DIMV * 2);
  U16* tok_bf = (U16*)take((size_t)MROWS * DIMV * 2);     // 32 MB, dead after GEMM2/tokpart
  U16* x_bf = (U16*)take((size_t)MROWS * DIMV * 2);
  U16* zx_bf = (U16*)take((size_t)MROWS * D_PROJ * 2);
  U16* xh_bf = (U16*)take((size_t)MROWS * D_INNER * 2);
  U16* bm_bf = (U16*)take((size_t)MROWS * 64 * 2);
  U16* cm_bf = (U16*)take((size_t)MROWS * 64 * 2);
  float* dtf = (float*)take((size_t)MROWS * 32 * 4);
  float* dAf = (float*)take((size_t)MROWS * 32 * 4);
  float* txtf = (float*)take(8 * 512 * 4);
  float* tokpart = (float*)take(16 * 8 * 512 * 4);
  float* yysum = (float*)take(8 * 1024 * 4);
  float* m2 = (float*)take(8 * 512 * 4);
  float* ylocal = (float*)take((size_t)256 * NCH * 32 * 4);
  float* aprod = (float*)take((size_t)256 * NCH * 4);
  // scan scratch overlays dead buffers (32 MB each now):
  float* hpart = (float*)img_bf;   // 8*NCH*32 blocks * 2048 f32 = 32 MB <= 64 MB
  float* wacc = (float*)tok_bf;    // 32 MB == tok_bf

  txt_kernel<<<8, 512, 0, stream>>>(text, W_txt, b_txt, txtf);
  cvt_f2b_kernel<<<(MROWS * HID / 4 + 255) / 256, 256, 0, stream>>>(image, img_bf, MROWS * HID / 4);
  transpose_cvt_kernel<<<dim3(DIMV / 32, HID / 32), dim3(32, 8), 0, stream>>>(W_in, wt_in, HID, DIMV, DIMV);
  transpose_cvt_kernel<<<dim3(D_PROJ_PAD / 32, DIMV / 32), dim3(32, 8), 0, stream>>>(W_zx, wt_zx, DIMV, D_PROJ, D_PROJ_PAD);

  gemm_kernel<1><<<dim3(MROWS / 128, DIMV / 128), 256, 0, stream>>>(img_bf, wt_in, tok_bf, b_in, txtf, MROWS, HID, DIMV);
  tokpart_kernel<<<dim3(8, 2, 16), 256, 0, stream>>>(tok_bf, tokpart);
  ln_kernel<<<MROWS, 128, 0, stream>>>(tok_bf, x_bf, norm_w, norm_b);

  gemm_kernel<0><<<dim3(MROWS / 128, D_PROJ_PAD / 128), 256, 0, stream>>>(x_bf, wt_zx, zx_bf, b_zx, nullptr, MROWS, DIMV, D_PROJ);

  dt_kernel<<<MROWS * 32 / 256, 256, 0, stream>>>(zx_bf, dt_bias, A_log, dtf, dAf);
  conv_kernel<<<dim3(MROWS / 4, 3), 384, 0, stream>>>(zx_bf, conv_w, conv_b, xh_bf, bm_bf, cm_bf);

  scan_chunk_kernel<<<8 * NCH * 32, 64, 0, stream>>>(xh_bf, bm_bf, cm_bf, zx_bf, dtf, dAf, Dp,
                                                     hpart, wacc, ylocal, aprod);
  scan_combine_kernel<<<256, 256, 0, stream>>>(hpart, wacc, ylocal, aprod, yysum);

  final1_kernel<<<dim3(8, 4), 128, 0, stream>>>(tokpart, yysum, W_blk, b_blk, m2);
  final2_kernel<<<dim3(8, 4), 256, 0, stream>>>(m2, W_out, b_out, out);
}

// Round 4
// 635.037 us; speedup vs baseline: 2.6056x; 1.1676x over previous
//
#include <hip/hip_runtime.h>

typedef unsigned short U16;
typedef __attribute__((ext_vector_type(2))) float f32x2;
typedef __attribute__((ext_vector_type(4))) float f32x4;
typedef __attribute__((ext_vector_type(8))) short short8;
typedef __attribute__((ext_vector_type(8))) __bf16 bf16x8;

#define Bsz 8
#define Lsz 4096
#define HID 1024
#define DIMV 512
#define D_INNER 1024
#define NHEADS 32
#define HEADDIM 32
#define D_STATE 64
#define CONV_DIM 1152
#define D_PROJ 2208
#define D_PROJ_PAD 2304
#define MROWS 32768
#define CL2 512        // scan chunk per block
#define NSUB 8         // sub-chunks of 64 per block
#define NCH 8          // Lsz / CL2

__device__ __forceinline__ float bf2f(U16 u) {
  return __builtin_bit_cast(float, (unsigned)(((unsigned)u) << 16));
}
__device__ __forceinline__ U16 f2bf(float f) {
  unsigned u = __builtin_bit_cast(unsigned, f);
  return (U16)((u + 0x7FFFu + ((u >> 16) & 1u)) >> 16);
}
__device__ __forceinline__ void gload_lds16(const void* g, void* l) {
  __builtin_amdgcn_global_load_lds((const __attribute__((address_space(1))) unsigned int*)g,
                                   (__attribute__((address_space(3))) unsigned int*)l, 16, 0, 0);
}

// ---------- tiny txt GEMM ----------
__global__ __launch_bounds__(512) void txt_kernel(const float* __restrict__ text,
                                                  const float* __restrict__ Wt,
                                                  const float* __restrict__ bt,
                                                  float* __restrict__ txt) {
  int b = blockIdx.x, j = threadIdx.x;
  float s = bt[j];
  const float* tp = text + (size_t)b * 77 * 768;
  for (int k = 0; k < 768; ++k) s += tp[k] * Wt[(size_t)k * 512 + j];
  txt[b * 512 + j] = s;
}

// ---------- f32 -> bf16 bulk convert ----------
__global__ __launch_bounds__(256) void cvt_f2b_kernel(const float* __restrict__ in,
                                                      U16* __restrict__ out, int n4) {
  int i = blockIdx.x * 256 + threadIdx.x;
  if (i < n4) {
    float4 v = reinterpret_cast<const float4*>(in)[i];
    ushort4 o;
    o.x = f2bf(v.x); o.y = f2bf(v.y); o.z = f2bf(v.z); o.w = f2bf(v.w);
    reinterpret_cast<ushort4*>(out)[i] = o;
  }
}

// ---------- transpose + convert weights ----------
__global__ __launch_bounds__(256) void transpose_cvt_kernel(const float* __restrict__ in,
                                                            U16* __restrict__ out,
                                                            int K, int N, int Npad) {
  __shared__ U16 tile[32][33];
  int n0 = blockIdx.x * 32, k0 = blockIdx.y * 32;
  int tx = threadIdx.x, ty = threadIdx.y;
  #pragma unroll
  for (int i = 0; i < 4; ++i) {
    int k = k0 + ty + i * 8, n = n0 + tx;
    float v = (n < N) ? in[(size_t)k * N + n] : 0.f;
    tile[ty + i * 8][tx] = f2bf(v);
  }
  __syncthreads();
  #pragma unroll
  for (int i = 0; i < 4; ++i) {
    int n = n0 + ty + i * 8;
    out[(size_t)n * K + k0 + tx] = tile[tx][ty + i * 8];
  }
}

// ---------- bf16 MFMA GEMM (unchanged) ----------
template <int EPI>
__global__ __launch_bounds__(256) void gemm_kernel(const U16* __restrict__ A,
                                                   const U16* __restrict__ Bt,
                                                   U16* __restrict__ C,
                                                   const float* __restrict__ bias,
                                                   const float* __restrict__ txtv,
                                                   int M, int K, int Nreal) {
  __shared__ alignas(16) U16 As[128 * 64];
  __shared__ alignas(16) U16 Bs[128 * 64];
  const int tid = threadIdx.x;
  const int wid = tid >> 6, lane = tid & 63;
  const int lhi = lane >> 4, llo = lane & 15;
  const int m0 = blockIdx.x * 128;
  const int n0 = blockIdx.y * 128;
  const int wr = wid >> 1, wc = wid & 1;
  f32x4 acc[4][4] = {};

  for (int k0 = 0; k0 < K; k0 += 64) {
    __syncthreads();
    #pragma unroll
    for (int is = 0; is < 4; ++is) {
      int qbase = is * 256 + wid * 64;
      int q = qbase + lane;
      int r = q >> 3;
      int cc = (q & 7) ^ (r & 7);
      gload_lds16(A + (size_t)(m0 + r) * K + k0 + cc * 8, &As[qbase * 8]);
    }
    #pragma unroll
    for (int is = 0; is < 4; ++is) {
      int qbase = is * 256 + wid * 64;
      int q = qbase + lane;
      int r = q >> 3;
      int cc = (q & 7) ^ (r & 7);
      gload_lds16(Bt + (size_t)(n0 + r) * K + k0 + cc * 8, &Bs[qbase * 8]);
    }
    __syncthreads();
    #pragma unroll
    for (int kk = 0; kk < 64; kk += 32) {
      bf16x8 av[4], bv[4];
      #pragma unroll
      for (int i = 0; i < 4; ++i) {
        int ra = wr * 64 + i * 16 + llo;
        short8 a = *reinterpret_cast<const short8*>(
            &As[ra * 64 + ((((kk >> 3) + lhi) ^ (ra & 7)) << 3)]);
        av[i] = __builtin_bit_cast(bf16x8, a);
        int rb = wc * 64 + i * 16 + llo;
        short8 b = *reinterpret_cast<const short8*>(
            &Bs[rb * 64 + ((((kk >> 3) + lhi) ^ (rb & 7)) << 3)]);
        bv[i] = __builtin_bit_cast(bf16x8, b);
      }
      #pragma unroll
      for (int i = 0; i < 4; ++i)
        #pragma unroll
        for (int j = 0; j < 4; ++j)
          acc[i][j] = __builtin_amdgcn_mfma_f32_16x16x32_bf16(av[i], bv[j], acc[i][j], 0, 0, 0);
    }
  }
  const int b = m0 >> 12;
  #pragma unroll
  for (int i = 0; i < 4; ++i) {
    int rbase = m0 + wr * 64 + i * 16 + lhi * 4;
    #pragma unroll
    for (int j = 0; j < 4; ++j) {
      int cg = n0 + wc * 64 + j * 16 + llo;
      if (cg < Nreal) {
        float badd = bias[cg] + (EPI ? txtv[b * 512 + cg] : 0.f);
        #pragma unroll
        for (int r = 0; r < 4; ++r)
          C[(size_t)(rbase + r) * Nreal + cg] = f2bf(acc[i][j][r] + badd);
      }
    }
  }
}

// ---------- LayerNorm ----------
__global__ __launch_bounds__(128) void ln_kernel(const U16* __restrict__ tok,
                                                 U16* __restrict__ xo,
                                                 const float* __restrict__ w,
                                                 const float* __restrict__ bb) {
  int row = blockIdx.x, tid = threadIdx.x;
  const U16* rp = tok + (size_t)row * 512 + tid * 4;
  uint2 raw = *reinterpret_cast<const uint2*>(rp);
  float f0 = bf2f((U16)(raw.x & 0xffff)), f1 = bf2f((U16)(raw.x >> 16));
  float f2 = bf2f((U16)(raw.y & 0xffff)), f3 = bf2f((U16)(raw.y >> 16));
  float s = f0 + f1 + f2 + f3;
  float q = f0 * f0 + f1 * f1 + f2 * f2 + f3 * f3;
  for (int m = 1; m < 64; m <<= 1) { s += __shfl_xor(s, m); q += __shfl_xor(q, m); }
  __shared__ float ss[2], qq[2];
  if ((tid & 63) == 0) { ss[tid >> 6] = s; qq[tid >> 6] = q; }
  __syncthreads();
  s = ss[0] + ss[1]; q = qq[0] + qq[1];
  float mu = s * (1.f / 512.f);
  float var = q * (1.f / 512.f) - mu * mu;
  float rs = rsqrtf(var + 1e-5f);
  int j0 = tid * 4;
  unsigned c0 = f2bf((f0 - mu) * rs * w[j0] + bb[j0]);
  unsigned c1 = f2bf((f1 - mu) * rs * w[j0 + 1] + bb[j0 + 1]);
  unsigned c2 = f2bf((f2 - mu) * rs * w[j0 + 2] + bb[j0 + 2]);
  unsigned c3 = f2bf((f3 - mu) * rs * w[j0 + 3] + bb[j0 + 3]);
  uint2 o; o.x = c0 | (c1 << 16); o.y = c2 | (c3 << 16);
  *reinterpret_cast<uint2*>(xo + (size_t)row * 512 + j0) = o;
}

// ---------- tok partial column sums ----------
__global__ __launch_bounds__(256) void tokpart_kernel(const U16* __restrict__ tok,
                                                      float* __restrict__ part) {
  int b = blockIdx.x, j = blockIdx.y * 256 + threadIdx.x, z = blockIdx.z;
  float s = 0.f;
  int l0 = z * 256;
  for (int l = l0; l < l0 + 256; ++l)
    s += bf2f(tok[((size_t)b * Lsz + l) * 512 + j]);
  part[(z * 8 + b) * 512 + j] = s;
}

// ---------- dt precompute: log-space decay (log2 units) ----------
__global__ __launch_bounds__(256) void dt_kernel(const U16* __restrict__ zx,
                                                 const float* __restrict__ dt_bias,
                                                 const float* __restrict__ A_log,
                                                 float* __restrict__ ldt2f,
                                                 float* __restrict__ ldA2f) {
  int idx = blockIdx.x * 256 + threadIdx.x;
  int row = idx >> 5, hh = idx & 31;
  float raw = bf2f(zx[(size_t)row * D_PROJ + 2176 + hh]) + dt_bias[hh];
  float dt = (raw > 20.f) ? raw : log1pf(__expf(raw));
  float A = -__expf(A_log[hh]);
  ldt2f[idx] = __log2f(dt);
  ldA2f[idx] = dt * A * 1.44269504088896f;
}

// ---------- conv(K=4)+silu with transposed-layout outputs ----------
// ct<16: z channels -> gz_t[b*1024+ch][L].  ct>=16: conv channels ->
// xh_t / bm_t,cm_t (transposed) and Bm,Cm (row-major).
__global__ __launch_bounds__(256) void conv_tr_kernel(
    const U16* __restrict__ zx, const float* __restrict__ cw,
    const float* __restrict__ cb, U16* __restrict__ Bmo, U16* __restrict__ Cmo,
    U16* __restrict__ xh_t, U16* __restrict__ gz_t,
    U16* __restrict__ bm_t, U16* __restrict__ cm_t) {
  __shared__ U16 tile[64 * 72];  // [c][l] pad 72
  const int lt = blockIdx.x, ct = blockIdx.y;
  const int r0 = lt * 64;
  const int b = r0 >> 12, l0 = r0 & 4095;
  const int tid = threadIdx.x;
  const int c = tid & 63, lqb = tid >> 6;

  if (ct < 16) {
    const int zc0 = ct * 64;
    #pragma unroll
    for (int it = 0; it < 4; ++it) {
      int lq4 = (lqb + it * 4) * 4;
      float v[4];
      #pragma unroll
      for (int j = 0; j < 4; ++j) {
        float z = bf2f(zx[(size_t)(r0 + lq4 + j) * D_PROJ + zc0 + c]);
        v[j] = z / (1.f + __expf(-z));
      }
      uint2 p2;
      p2.x = (unsigned)f2bf(v[0]) | ((unsigned)f2bf(v[1]) << 16);
      p2.y = (unsigned)f2bf(v[2]) | ((unsigned)f2bf(v[3]) << 16);
      *reinterpret_cast<uint2*>(reinterpret_cast<char*>(tile) + (size_t)c * 144 + lq4 * 2) = p2;
    }
    __syncthreads();
    int c2 = tid >> 2, seg = tid & 3;
    const char* src = reinterpret_cast<const char*>(tile) + (size_t)c2 * 144 + seg * 32;
    f32x4 a = *reinterpret_cast<const f32x4*>(src);
    f32x4 bq = *reinterpret_cast<const f32x4*>(src + 16);
    U16* dst = gz_t + ((size_t)b * 1024 + zc0 + c2) * 4096 + l0 + seg * 16;
    *reinterpret_cast<f32x4*>(dst) = a;
    *reinterpret_cast<f32x4*>(dst + 8) = bq;
  } else {
    const int cc = (ct - 16) * 64 + c;
    const float4 w4 = *reinterpret_cast<const float4*>(cw + cc * 4);
    const float cbv = cb[cc];
    #pragma unroll
    for (int it = 0; it < 4; ++it) {
      int lq4 = (lqb + it * 4) * 4;
      float v7[7];
      #pragma unroll
      for (int k = 0; k < 7; ++k) {
        int lrel = lq4 + k - 3;
        v7[k] = (l0 + lrel >= 0)
                    ? bf2f(zx[(size_t)(r0 + lrel) * D_PROJ + D_INNER + cc])
                    : 0.f;
      }
      float o[4];
      #pragma unroll
      for (int j = 0; j < 4; ++j) {
        float acc = cbv + v7[j] * w4.x + v7[j + 1] * w4.y + v7[j + 2] * w4.z + v7[j + 3] * w4.w;
        o[j] = acc / (1.f + __expf(-acc));
      }
      uint2 p2;
      p2.x = (unsigned)f2bf(o[0]) | ((unsigned)f2bf(o[1]) << 16);
      p2.y = (unsigned)f2bf(o[2]) | ((unsigned)f2bf(o[3]) << 16);
      *reinterpret_cast<uint2*>(reinterpret_cast<char*>(tile) + (size_t)c * 144 + lq4 * 2) = p2;
      if (cc >= 1024) {
        U16* outp = (cc < 1088) ? Bmo : Cmo;
        int n = cc & 63;
        #pragma unroll
        for (int j = 0; j < 4; ++j)
          outp[(size_t)(r0 + lq4 + j) * 64 + n] = f2bf(o[j]);
      }
    }
    __syncthreads();
    int c2 = tid >> 2, seg = tid & 3;
    const char* src = reinterpret_cast<const char*>(tile) + (size_t)c2 * 144 + seg * 32;
    f32x4 a = *reinterpret_cast<const f32x4*>(src);
    f32x4 bq = *reinterpret_cast<const f32x4*>(src + 16);
    int cc2 = (ct - 16) * 64 + c2;
    U16* dst;
    if (cc2 < 1024)      dst = xh_t + ((size_t)b * 1024 + cc2) * 4096 + l0 + seg * 16;
    else if (cc2 < 1088) dst = bm_t + ((size_t)(b * 64 + cc2 - 1024)) * 4096 + l0 + seg * 16;
    else                 dst = cm_t + ((size_t)(b * 64 + cc2 - 1088)) * 4096 + l0 + seg * 16;
    *reinterpret_cast<f32x4*>(dst) = a;
    *reinterpret_cast<f32x4*>(dst + 8) = bq;
  }
}

// ---------- SSD chunked scan via MFMA: one (b,ci,h) per 64-thread block ----------
__global__ __launch_bounds__(64, 2) void scan_chunk_kernel(
    const U16* __restrict__ xh_t, const U16* __restrict__ gz_t,
    const U16* __restrict__ Bm, const U16* __restrict__ Cm,
    const U16* __restrict__ bm_t, const U16* __restrict__ cm_t,
    const float* __restrict__ ldt2f, const float* __restrict__ ldA2f,
    const float* __restrict__ Dp,
    float* __restrict__ hpart, float* __restrict__ wacc,
    float* __restrict__ ylocal, float* __restrict__ aprod) {
  const int bx = blockIdx.x;
  const int hh = bx & 31, ci = (bx >> 5) & 7, b = bx >> 8;
  const int l = threadIdx.x;
  const int tl = l & 15, lg = l >> 4;

  __shared__ U16 Msm[64 * 72];  // [t][s] pad 72
  __shared__ float qsm[64], la2sm[64], casm[64], cfsm[64];
  __shared__ float ysm[32];

  #pragma unroll
  for (int i = 0; i < 9; ++i)
    *reinterpret_cast<f32x4*>(reinterpret_cast<char*>(Msm) + (size_t)l * 144 + i * 16) =
        f32x4{0.f, 0.f, 0.f, 0.f};
  __syncthreads();

  f32x4 hC[2][4] = {};
  f32x4 WB[2][4] = {};
  float corrv[2][4] = {};
  float ylac[2] = {0.f, 0.f}, dxac[2] = {0.f, 0.f};
  float capfx = 1.f;
  const size_t xgrow = ((size_t)b * 1024 + hh * 32) * 4096;

  for (int sc = 0; sc < NSUB; ++sc) {
    const int lglob = ci * CL2 + sc * 64;
    const int r0g = b * 4096 + lglob;

    // per-step scalars: inclusive prefix of log2(dA)
    float ldA2 = ldA2f[(size_t)(r0g + l) * 32 + hh];
    float ldt2 = ldt2f[(size_t)(r0g + l) * 32 + hh];
    float la = ldA2;
    #pragma unroll
    for (int d = 1; d < 64; d <<= 1) {
      float o = __shfl_up(la, d);
      if (l >= d) la += o;
    }
    float laend = __shfl(la, 63);
    qsm[l] = ldt2 - la;
    la2sm[l] = la;
    casm[l] = exp2f(la);
    cfsm[l] = exp2f(laend + ldt2 - la);
    __syncthreads();

    // ---- matmul1: G'[s][t] = sum_n B[s,n] C[t,n], only tiles si<=ti ----
    f32x4 g[10];
    #pragma unroll
    for (int i = 0; i < 10; ++i) g[i] = f32x4{0.f, 0.f, 0.f, 0.f};
    #pragma unroll
    for (int k = 0; k < 2; ++k) {
      bf16x8 af[4], cf4[4];
      #pragma unroll
      for (int si = 0; si < 4; ++si)
        af[si] = *reinterpret_cast<const bf16x8*>(
            Bm + (size_t)(r0g + si * 16 + tl) * 64 + k * 32 + lg * 8);
      #pragma unroll
      for (int ti = 0; ti < 4; ++ti)
        cf4[ti] = *reinterpret_cast<const bf16x8*>(
            Cm + (size_t)(r0g + ti * 16 + tl) * 64 + k * 32 + lg * 8);
      int idx = 0;
      #pragma unroll
      for (int si = 0; si < 4; ++si)
        #pragma unroll
        for (int ti = si; ti < 4; ++ti) {
          g[idx] = __builtin_amdgcn_mfma_f32_16x16x32_bf16(af[si], cf4[ti], g[idx], 0, 0, 0);
          ++idx;
        }
    }

    // ---- mask + scale + write M (bf16) ----
    {
      int idx = 0;
      #pragma unroll
      for (int si = 0; si < 4; ++si) {
        f32x4 q4 = *reinterpret_cast<const f32x4*>(&qsm[si * 16 + lg * 4]);
        #pragma unroll
        for (int ti = si; ti < 4; ++ti) {
          float lat = la2sm[ti * 16 + tl];
          f32x4 gv = g[idx]; ++idx;
          float v[4];
          #pragma unroll
          for (int r = 0; r < 4; ++r) {
            float val = gv[r] * exp2f(lat + q4[r]);
            if (si == ti) val = (lg * 4 + r <= tl) ? val : 0.f;
            v[r] = val;
          }
          uint2 pk;
          pk.x = (unsigned)f2bf(v[0]) | ((unsigned)f2bf(v[1]) << 16);
          pk.y = (unsigned)f2bf(v[2]) | ((unsigned)f2bf(v[3]) << 16);
          *reinterpret_cast<uint2*>(reinterpret_cast<char*>(Msm) +
                                    (size_t)(ti * 16 + tl) * 144 + (size_t)(si * 16 + lg * 4) * 2) = pk;
        }
      }
    }
    __syncthreads();

    // ---- matmul2: Y[t][p] = M X ; gated accumulation ----
    {
      bf16x8 xb[2][2];
      #pragma unroll
      for (int pt = 0; pt < 2; ++pt)
        #pragma unroll
        for (int ks = 0; ks < 2; ++ks)
          xb[pt][ks] = *reinterpret_cast<const bf16x8*>(
              xh_t + xgrow + (size_t)(pt * 16 + tl) * 4096 + lglob + ks * 32 + lg * 8);
      #pragma unroll
      for (int tt = 0; tt < 4; ++tt) {
        f32x4 y[2] = {f32x4{0.f, 0.f, 0.f, 0.f}, f32x4{0.f, 0.f, 0.f, 0.f}};
        #pragma unroll
        for (int ks = 0; ks < 2; ++ks) {
          bf16x8 mf = *reinterpret_cast<const bf16x8*>(
              reinterpret_cast<char*>(Msm) + (size_t)(tt * 16 + tl) * 144 + (ks * 32 + lg * 8) * 2);
          #pragma unroll
          for (int pt = 0; pt < 2; ++pt)
            y[pt] = __builtin_amdgcn_mfma_f32_16x16x32_bf16(mf, xb[pt][ks], y[pt], 0, 0, 0);
        }
        #pragma unroll
        for (int pt = 0; pt < 2; ++pt) {
          size_t ro = xgrow + (size_t)(pt * 16 + tl) * 4096 + lglob + tt * 16 + lg * 4;
          uint2 gz2 = *reinterpret_cast<const uint2*>(gz_t + ro);
          uint2 xx2 = *reinterpret_cast<const uint2*>(xh_t + ro);
          float gzv[4] = {bf2f((U16)(gz2.x & 0xffff)), bf2f((U16)(gz2.x >> 16)),
                          bf2f((U16)(gz2.y & 0xffff)), bf2f((U16)(gz2.y >> 16))};
          float xxv[4] = {bf2f((U16)(xx2.x & 0xffff)), bf2f((U16)(xx2.x >> 16)),
                          bf2f((U16)(xx2.y & 0xffff)), bf2f((U16)(xx2.y >> 16))};
          #pragma unroll
          for (int r = 0; r < 4; ++r) {
            ylac[pt] = fmaf(gzv[r], y[pt][r], ylac[pt]);
            dxac[pt] = fmaf(gzv[r], xxv[r], dxac[pt]);
          }
        }
      }
    }

    // ---- matmul3 (W = (gz*ca)^T C) and state update (h = (x*coef)^T B) ----
    bf16x8 ga[2][2], xa[2][2];
    #pragma unroll
    for (int pt = 0; pt < 2; ++pt)
      #pragma unroll
      for (int kt = 0; kt < 2; ++kt) {
        size_t ro = xgrow + (size_t)(pt * 16 + tl) * 4096 + lglob + kt * 32 + lg * 8;
        short8 graw = *reinterpret_cast<const short8*>(gz_t + ro);
        short8 xraw = *reinterpret_cast<const short8*>(xh_t + ro);
        const float* cap = &casm[kt * 32 + lg * 8];
        const float* cfp = &cfsm[kt * 32 + lg * 8];
        short8 gs, xs8;
        #pragma unroll
        for (int j = 0; j < 8; ++j) {
          gs[j] = (short)f2bf(bf2f((U16)graw[j]) * cap[j]);
          xs8[j] = (short)f2bf(bf2f((U16)xraw[j]) * cfp[j]);
        }
        ga[pt][kt] = __builtin_bit_cast(bf16x8, gs);
        xa[pt][kt] = __builtin_bit_cast(bf16x8, xs8);
      }
    f32x4 ws[2][4] = {};
    f32x4 hs[2][4] = {};
    #pragma unroll
    for (int kt = 0; kt < 2; ++kt) {
      bf16x8 cbf[4], bbf[4];
      #pragma unroll
      for (int nt = 0; nt < 4; ++nt) {
        cbf[nt] = *reinterpret_cast<const bf16x8*>(
            cm_t + (size_t)(b * 64 + nt * 16 + tl) * 4096 + lglob + kt * 32 + lg * 8);
        bbf[nt] = *reinterpret_cast<const bf16x8*>(
            bm_t + (size_t)(b * 64 + nt * 16 + tl) * 4096 + lglob + kt * 32 + lg * 8);
      }
      #pragma unroll
      for (int pt = 0; pt < 2; ++pt)
        #pragma unroll
        for (int nt = 0; nt < 4; ++nt) {
          ws[pt][nt] = __builtin_amdgcn_mfma_f32_16x16x32_bf16(ga[pt][kt], cbf[nt], ws[pt][nt], 0, 0, 0);
          hs[pt][nt] = __builtin_amdgcn_mfma_f32_16x16x32_bf16(xa[pt][kt], bbf[nt], hs[pt][nt], 0, 0, 0);
        }
    }

    // ---- inter-sub correction + accumulations ----
    float cs = exp2f(laend);
    #pragma unroll
    for (int pt = 0; pt < 2; ++pt) {
      f32x4 a4 = hC[pt][0] * ws[pt][0] + hC[pt][1] * ws[pt][1] +
                 hC[pt][2] * ws[pt][2] + hC[pt][3] * ws[pt][3];
      #pragma unroll
      for (int r = 0; r < 4; ++r) {
        float cc = a4[r];
        cc += __shfl_xor(cc, 1); cc += __shfl_xor(cc, 2);
        cc += __shfl_xor(cc, 4); cc += __shfl_xor(cc, 8);
        corrv[pt][r] += cc;
      }
      #pragma unroll
      for (int nt = 0; nt < 4; ++nt) {
        WB[pt][nt] = WB[pt][nt] + ws[pt][nt] * capfx;
        hC[pt][nt] = hC[pt][nt] * cs + hs[pt][nt];
      }
    }
    capfx *= cs;
    __syncthreads();
  }

  // ---- epilogue ----
  #pragma unroll
  for (int pt = 0; pt < 2; ++pt)
    #pragma unroll
    for (int nt = 0; nt < 4; ++nt) {
      size_t slot = (size_t)bx * 2048 + (size_t)((pt * 4 + nt) * 64 + l) * 4;
      *reinterpret_cast<f32x4*>(hpart + slot) = hC[pt][nt];
      *reinterpret_cast<f32x4*>(wacc + slot) = WB[pt][nt];
    }
  const float Dh = Dp[hh];
  #pragma unroll
  for (int pt = 0; pt < 2; ++pt) {
    float yv = ylac[pt] + Dh * dxac[pt];
    yv += __shfl_xor(yv, 16);
    yv += __shfl_xor(yv, 32);
    if (l < 16) ysm[pt * 16 + l] = yv;
  }
  __syncthreads();
  if (tl == 0) {
    #pragma unroll
    for (int pt = 0; pt < 2; ++pt)
      #pragma unroll
      for (int r = 0; r < 4; ++r)
        ysm[pt * 16 + lg * 4 + r] += corrv[pt][r];
  }
  __syncthreads();
  if (l < 32) ylocal[(size_t)bx * 32 + l] = ysm[l];
  if (l == 0) aprod[bx] = capfx;
}

// ---------- sequential combine across chunks ----------
__global__ __launch_bounds__(64) void scan_combine_kernel(
    const float* __restrict__ hpart, const float* __restrict__ wacc,
    const float* __restrict__ ylocal, const float* __restrict__ aprod,
    float* __restrict__ yysum) {
  const int bh = blockIdx.x;
  const int b = bh >> 5, hh = bh & 31;
  const int l = threadIdx.x, tl = l & 15, lg = l >> 4;
  __shared__ float ysm[32];
  f32x4 hr[8] = {};
  float cv[8] = {};
  float ylsum = 0.f;
  for (int ci = 0; ci < NCH; ++ci) {
    int bx = (b * NCH + ci) * 32 + hh;
    size_t base = (size_t)bx * 2048 + (size_t)l * 4;
    f32x4 w[8], p[8];
    #pragma unroll
    for (int t8 = 0; t8 < 8; ++t8) {
      w[t8] = *reinterpret_cast<const f32x4*>(wacc + base + t8 * 256);
      p[t8] = *reinterpret_cast<const f32x4*>(hpart + base + t8 * 256);
    }
    float ap = aprod[bx];
    #pragma unroll
    for (int pt = 0; pt < 2; ++pt) {
      f32x4 a4 = hr[pt * 4] * w[pt * 4] + hr[pt * 4 + 1] * w[pt * 4 + 1] +
                 hr[pt * 4 + 2] * w[pt * 4 + 2] + hr[pt * 4 + 3] * w[pt * 4 + 3];
      #pragma unroll
      for (int r = 0; r < 4; ++r) cv[pt * 4 + r] += a4[r];
    }
    #pragma unroll
    for (int t8 = 0; t8 < 8; ++t8) hr[t8] = hr[t8] * ap + p[t8];
    if (l < 32) ylsum += ylocal[(size_t)bx * 32 + l];
  }
  #pragma unroll
  for (int i = 0; i < 8; ++i) {
    cv[i] += __shfl_xor(cv[i], 1); cv[i] += __shfl_xor(cv[i], 2);
    cv[i] += __shfl_xor(cv[i], 4); cv[i] += __shfl_xor(cv[i], 8);
  }
  if (l < 32) ysm[l] = ylsum;
  __syncthreads();
  if (tl == 0) {
    #pragma unroll
    for (int pt = 0; pt < 2; ++pt)
      #pragma unroll
      for (int r = 0; r < 4; ++r)
        ysm[pt * 16 + lg * 4 + r] += cv[pt * 4 + r];
  }
  __syncthreads();
  if (l < 32) yysum[(size_t)b * 1024 + hh * 32 + l] = ysm[l];
}

// ---------- folded epilogue ----------
__global__ __launch_bounds__(128) void final1_kernel(const float* __restrict__ tokpart,
                                                     const float* __restrict__ yysum,
                                                     const float* __restrict__ Wb,
                                                     const float* __restrict__ bb,
                                                     float* __restrict__ m2) {
  int b = blockIdx.x, j = blockIdx.y * 128 + threadIdx.x;
  float tm = 0.f;
  #pragma unroll
  for (int z = 0; z < 16; ++z) tm += tokpart[(z * 8 + b) * 512 + j];
  float s = 0.f;
  for (int d = 0; d < 1024; ++d) s += yysum[b * 1024 + d] * Wb[(size_t)d * 512 + j];
  m2[b * 512 + j] = (tm + s) * (1.f / (float)Lsz) + bb[j];
}

__global__ __launch_bounds__(256) void final2_kernel(const float* __restrict__ m2,
                                                     const float* __restrict__ Wo,
                                                     const float* __restrict__ bo,
                                                     float* __restrict__ out) {
  int b = blockIdx.x, o = blockIdx.y * 256 + threadIdx.x;
  float s = 0.f;
  for (int j = 0; j < 512; ++j) s += m2[b * 512 + j] * Wo[(size_t)j * 1024 + o];
  out[b * 1024 + o] = s + bo[o];
}

extern "C" void kernel_launch(void* const* d_in, const int* in_sizes, int n_in,
                              void* d_out, int out_size, void* d_ws, size_t ws_size,
                              hipStream_t stream) {
  const float* image = (const float*)d_in[0];
  const float* text = (const float*)d_in[1];
  const float* W_in = (const float*)d_in[2];
  const float* b_in = (const float*)d_in[3];
  const float* W_txt = (const float*)d_in[4];
  const float* b_txt = (const float*)d_in[5];
  const float* norm_w = (const float*)d_in[6];
  const float* norm_b = (const float*)d_in[7];
  const float* W_zx = (const float*)d_in[8];
  const float* b_zx = (const float*)d_in[9];
  const float* conv_w = (const float*)d_in[10];
  const float* conv_b = (const float*)d_in[11];
  const float* dt_bias = (const float*)d_in[12];
  const float* A_log = (const float*)d_in[13];
  const float* Dp = (const float*)d_in[14];
  const float* W_blk = (const float*)d_in[15];
  const float* b_blk = (const float*)d_in[16];
  const float* W_out = (const float*)d_in[17];
  const float* b_out = (const float*)d_in[18];
  float* out = (float*)d_out;

  char* ws = (char*)d_ws;
  size_t off = 0;
  auto take = [&](size_t bytes) {
    char* p = ws + off;
    off = (off + bytes + 255) & ~(size_t)255;
    return p;
  };
  U16* img_bf = (U16*)take((size_t)MROWS * HID * 2);   // dead after GEMM1 -> gz_t
  U16* wt_in = (U16*)take((size_t)DIMV * HID * 2);
  U16* wt_zx = (U16*)take((size_t)D_PROJ_PAD * DIMV * 2);
  U16* tok_bf = (U16*)take((size_t)MROWS * DIMV * 2);  // dead after GEMM2 -> hpart
  U16* x_bf = (U16*)take((size_t)MROWS * DIMV * 2);    // dead after GEMM2 -> wacc
  U16* zx_bf = (U16*)take((size_t)MROWS * D_PROJ * 2);
  U16* xh_t = (U16*)take((size_t)MROWS * D_INNER * 2);
  U16* bm_bf = (U16*)take((size_t)MROWS * 64 * 2);
  U16* cm_bf = (U16*)take((size_t)MROWS * 64 * 2);
  U16* bm_t = (U16*)take((size_t)MROWS * 64 * 2);
  U16* cm_t = (U16*)take((size_t)MROWS * 64 * 2);
  float* ldt2f = (float*)take((size_t)MROWS * 32 * 4);
  float* ldA2f = (float*)take((size_t)MROWS * 32 * 4);
  float* txtf = (float*)take(8 * 512 * 4);
  float* tokpart = (float*)take(16 * 8 * 512 * 4);
  float* yysum = (float*)take(8 * 1024 * 4);
  float* m2 = (float*)take(8 * 512 * 4);
  float* ylocal = (float*)take((size_t)2048 * 32 * 4);
  float* aprod = (float*)take((size_t)2048 * 4);
  U16* gz_t = img_bf;            // 64 MB overlay
  float* hpart = (float*)tok_bf; // 16 MB <= 32 MB
  float* wacc = (float*)x_bf;    // 16 MB <= 32 MB

  txt_kernel<<<8, 512, 0, stream>>>(text, W_txt, b_txt, txtf);
  cvt_f2b_kernel<<<(MROWS * HID / 4 + 255) / 256, 256, 0, stream>>>(image, img_bf, MROWS * HID / 4);
  transpose_cvt_kernel<<<dim3(DIMV / 32, HID / 32), dim3(32, 8), 0, stream>>>(W_in, wt_in, HID, DIMV, DIMV);
  transpose_cvt_kernel<<<dim3(D_PROJ_PAD / 32, DIMV / 32), dim3(32, 8), 0, stream>>>(W_zx, wt_zx, DIMV, D_PROJ, D_PROJ_PAD);

  gemm_kernel<1><<<dim3(MROWS / 128, DIMV / 128), 256, 0, stream>>>(img_bf, wt_in, tok_bf, b_in, txtf, MROWS, HID, DIMV);
  tokpart_kernel<<<dim3(8, 2, 16), 256, 0, stream>>>(tok_bf, tokpart);
  ln_kernel<<<MROWS, 128, 0, stream>>>(tok_bf, x_bf, norm_w, norm_b);

  gemm_kernel<0><<<dim3(MROWS / 128, D_PROJ_PAD / 128), 256, 0, stream>>>(x_bf, wt_zx, zx_bf, b_zx, nullptr, MROWS, DIMV, D_PROJ);

  dt_kernel<<<MROWS * 32 / 256, 256, 0, stream>>>(zx_bf, dt_bias, A_log, ldt2f, ldA2f);
  conv_tr_kernel<<<dim3(MROWS / 64, 34), 256, 0, stream>>>(zx_bf, conv_w, conv_b, bm_bf, cm_bf,
                                                           xh_t, gz_t, bm_t, cm_t);

  scan_chunk_kernel<<<8 * NCH * 32, 64, 0, stream>>>(xh_t, gz_t, bm_bf, cm_bf, bm_t, cm_t,
                                                     ldt2f, ldA2f, Dp, hpart, wacc, ylocal, aprod);
  scan_combine_kernel<<<256, 64, 0, stream>>>(hpart, wacc, ylocal, aprod, yysum);

  final1_kernel<<<dim3(8, 4), 128, 0, stream>>>(tokpart, yysum, W_blk, b_blk, m2);
  final2_kernel<<<dim3(8, 4), 256, 0, stream>>>(m2, W_out, b_out, out);
}